// Round 1
// baseline (2278.785 us; speedup 1.0000x reference)
//
#include <hip/hip_runtime.h>
#include <math.h>

// Problem constants (B=1)
#define TT 4096
#define CC 1024
#define NH 16
#define HD 64
#define HP 32   // HD/2

// ---------------------------------------------------------------------------
// Tiled fp32 GEMM:  out[t, o] = sum_c A[t, c] * W[o, c]   (A row-major TxC,
// W row-major OxC -> this is x @ W^T, both operands row-contiguous in K)
// BM=BN=64, BK=16, 256 threads, each thread computes a 4x4 sub-tile.
// MODE 0: store row-major [T][C] (output projection)
// MODE 1: store as [h][T][d] with RoPE applied (q, k)
// MODE 2: store as [h][T][d] without RoPE (v)
// ---------------------------------------------------------------------------
template <int MODE>
__global__ __launch_bounds__(256) void gemm_xwT(
    const float* __restrict__ A, const float* __restrict__ W,
    const float* __restrict__ fcos, const float* __restrict__ fsin,
    float* __restrict__ dst)
{
    __shared__ float As[64][17];
    __shared__ float Ws[64][17];

    const int bm = blockIdx.x * 64;   // rows (t)
    const int bn = blockIdx.y * 64;   // cols (o)
    const int tid = threadIdx.x;
    const int ty = tid >> 4;          // 0..15
    const int tx = tid & 15;          // 0..15

    float acc[4][4] = {};

    for (int kk = 0; kk < CC; kk += 16) {
        #pragma unroll
        for (int e = 0; e < 4; ++e) {
            int idx = tid + e * 256;
            int r = idx >> 4, c = idx & 15;
            As[r][c] = A[(size_t)(bm + r) * CC + kk + c];
            Ws[r][c] = W[(size_t)(bn + r) * CC + kk + c];
        }
        __syncthreads();
        #pragma unroll
        for (int kx = 0; kx < 16; ++kx) {
            float a[4], b[4];
            #pragma unroll
            for (int i = 0; i < 4; ++i) a[i] = As[ty * 4 + i][kx];
            #pragma unroll
            for (int j = 0; j < 4; ++j) b[j] = Ws[tx * 4 + j][kx];
            #pragma unroll
            for (int i = 0; i < 4; ++i)
                #pragma unroll
                for (int j = 0; j < 4; ++j)
                    acc[i][j] += a[i] * b[j];
        }
        __syncthreads();
    }

    #pragma unroll
    for (int i = 0; i < 4; ++i) {
        const int t = bm + ty * 4 + i;
        if (MODE == 1) {
            // RoPE on the two even/odd pairs inside this thread's 4 columns
            #pragma unroll
            for (int jp = 0; jp < 2; ++jp) {
                const int c0 = bn + tx * 4 + jp * 2;   // even column
                const int pp = (c0 & 63) >> 1;         // pair idx within head
                const float cv = fcos[(size_t)t * HP + pp];
                const float sv = fsin[(size_t)t * HP + pp];
                const float a0 = acc[i][jp * 2];
                const float a1 = acc[i][jp * 2 + 1];
                const float o0 = a0 * cv - a1 * sv;
                const float o1 = a0 * sv + a1 * cv;
                const int head = c0 >> 6, dd = c0 & 63;
                dst[((size_t)head * TT + t) * HD + dd]     = o0;
                dst[((size_t)head * TT + t) * HD + dd + 1] = o1;
            }
        } else if (MODE == 2) {
            #pragma unroll
            for (int j = 0; j < 4; ++j) {
                const int c = bn + tx * 4 + j;
                const int head = c >> 6, dd = c & 63;
                dst[((size_t)head * TT + t) * HD + dd] = acc[i][j];
            }
        } else {
            #pragma unroll
            for (int j = 0; j < 4; ++j)
                dst[(size_t)t * CC + bn + tx * 4 + j] = acc[i][j];
        }
    }
}

// ---------------------------------------------------------------------------
// fp32 flash attention, causal.  One block per (q-block of 64 rows, head).
// q,k,v are [h][T][d]; y written as [T][C] (col = head*64 + dd).
// ---------------------------------------------------------------------------
__global__ __launch_bounds__(256) void flash_attn(
    const float* __restrict__ q, const float* __restrict__ k,
    const float* __restrict__ v, float* __restrict__ y)
{
    const int qb   = blockIdx.x;   // 0..63
    const int head = blockIdx.y;   // 0..15
    const int tid = threadIdx.x;
    const int ty = tid >> 4;       // 0..15
    const int tx = tid & 15;       // 0..15

    __shared__ float Qs[64][65];
    __shared__ float Ks[64][65];
    __shared__ float Vs[64][65];
    __shared__ float Ss[64][65];
    __shared__ float m_s[64], l_s[64], alpha_s[64];

    const float* qh = q + (size_t)head * TT * HD;
    const float* kh = k + (size_t)head * TT * HD;
    const float* vh = v + (size_t)head * TT * HD;

    #pragma unroll
    for (int e = 0; e < 16; ++e) {
        int idx = tid + e * 256;
        int r = idx >> 6, c = idx & 63;
        Qs[r][c] = qh[(size_t)(qb * 64 + r) * HD + c];
    }
    if (tid < 64) { m_s[tid] = -1e30f; l_s[tid] = 0.0f; }
    float yacc[4][4] = {};
    __syncthreads();

    const float scale = 0.125f;  // 1/sqrt(64)

    for (int kb = 0; kb <= qb; ++kb) {
        #pragma unroll
        for (int e = 0; e < 16; ++e) {
            int idx = tid + e * 256;
            int r = idx >> 6, c = idx & 63;
            Ks[r][c] = kh[(size_t)(kb * 64 + r) * HD + c];
            Vs[r][c] = vh[(size_t)(kb * 64 + r) * HD + c];
        }
        __syncthreads();

        // S = (Q K^T) * scale with causal mask
        float s[4][4] = {};
        #pragma unroll 8
        for (int dd = 0; dd < 64; ++dd) {
            float a[4], b[4];
            #pragma unroll
            for (int i = 0; i < 4; ++i) a[i] = Qs[ty * 4 + i][dd];
            #pragma unroll
            for (int j = 0; j < 4; ++j) b[j] = Ks[tx * 4 + j][dd];
            #pragma unroll
            for (int i = 0; i < 4; ++i)
                #pragma unroll
                for (int j = 0; j < 4; ++j)
                    s[i][j] += a[i] * b[j];
        }
        #pragma unroll
        for (int i = 0; i < 4; ++i) {
            #pragma unroll
            for (int j = 0; j < 4; ++j) {
                const int r = qb * 64 + ty * 4 + i;
                const int c = kb * 64 + tx * 4 + j;
                float val = s[i][j] * scale;
                if (c > r) val = -1e30f;
                Ss[ty * 4 + i][tx * 4 + j] = val;
            }
        }
        __syncthreads();

        // online softmax per row (threads 0..63 each own a row)
        if (tid < 64) {
            const float mold = m_s[tid];
            float mx = mold;
            for (int c2 = 0; c2 < 64; ++c2) mx = fmaxf(mx, Ss[tid][c2]);
            const float al = __expf(mold - mx);
            float sum = 0.0f;
            for (int c2 = 0; c2 < 64; ++c2) {
                float p = __expf(Ss[tid][c2] - mx);
                Ss[tid][c2] = p;
                sum += p;
            }
            m_s[tid] = mx;
            l_s[tid] = l_s[tid] * al + sum;
            alpha_s[tid] = al;
        }
        __syncthreads();

        // y = y*alpha + P V
        float al[4];
        #pragma unroll
        for (int i = 0; i < 4; ++i) al[i] = alpha_s[ty * 4 + i];
        #pragma unroll
        for (int i = 0; i < 4; ++i)
            #pragma unroll
            for (int j = 0; j < 4; ++j)
                yacc[i][j] *= al[i];
        #pragma unroll 8
        for (int kx = 0; kx < 64; ++kx) {
            float p[4], vv[4];
            #pragma unroll
            for (int i = 0; i < 4; ++i) p[i] = Ss[ty * 4 + i][kx];
            #pragma unroll
            for (int j = 0; j < 4; ++j) vv[j] = Vs[kx][tx * 4 + j];
            #pragma unroll
            for (int i = 0; i < 4; ++i)
                #pragma unroll
                for (int j = 0; j < 4; ++j)
                    yacc[i][j] += p[i] * vv[j];
        }
        __syncthreads();
    }

    // write y [T][C], normalized
    #pragma unroll
    for (int i = 0; i < 4; ++i) {
        const int t = qb * 64 + ty * 4 + i;
        const float linv = 1.0f / l_s[ty * 4 + i];
        #pragma unroll
        for (int j = 0; j < 4; ++j) {
            const int c = head * HD + tx * 4 + j;
            y[(size_t)t * CC + c] = yacc[i][j] * linv;
        }
    }
}

extern "C" void kernel_launch(void* const* d_in, const int* in_sizes, int n_in,
                              void* d_out, int out_size, void* d_ws, size_t ws_size,
                              hipStream_t stream) {
    const float* x    = (const float*)d_in[0];
    const float* fcos = (const float*)d_in[1];
    const float* fsin = (const float*)d_in[2];
    const float* Wq   = (const float*)d_in[3];
    const float* Wk   = (const float*)d_in[4];
    const float* Wv   = (const float*)d_in[5];
    const float* Wo   = (const float*)d_in[6];
    float* out = (float*)d_out;

    // workspace: q, k, v in [h][T][d]; y in [T][C]
    float* q_ws = (float*)d_ws;
    float* k_ws = q_ws + (size_t)NH * TT * HD;
    float* v_ws = k_ws + (size_t)NH * TT * HD;
    float* y_ws = v_ws + (size_t)NH * TT * HD;

    dim3 ggrid(TT / 64, CC / 64);
    dim3 gblock(256);

    gemm_xwT<1><<<ggrid, gblock, 0, stream>>>(x, Wq, fcos, fsin, q_ws);
    gemm_xwT<1><<<ggrid, gblock, 0, stream>>>(x, Wk, fcos, fsin, k_ws);
    gemm_xwT<2><<<ggrid, gblock, 0, stream>>>(x, Wv, fcos, fsin, v_ws);

    dim3 agrid(TT / 64, NH);
    flash_attn<<<agrid, gblock, 0, stream>>>(q_ws, k_ws, v_ws, y_ws);

    gemm_xwT<0><<<ggrid, gblock, 0, stream>>>(y_ws, Wo, fcos, fsin, out);
}

// Round 2
// 321.837 us; speedup vs baseline: 7.0805x; 7.0805x over previous
//
#include <hip/hip_runtime.h>
#include <math.h>

#define TT 4096
#define CC 1024
#define NH 16
#define HD 64

typedef unsigned short ushortT;
typedef __attribute__((ext_vector_type(8))) short short8;
typedef __attribute__((ext_vector_type(4))) float f32x4;

#define GLOAD_LDS16(gp, lp)                                                   \
    __builtin_amdgcn_global_load_lds(                                         \
        (const __attribute__((address_space(1))) void*)(gp),                  \
        (__attribute__((address_space(3))) void*)(lp), 16, 0, 0)

__device__ __forceinline__ ushortT f2bf(float f) {
    unsigned u = __float_as_uint(f);
    unsigned r = (u + 0x7FFFu + ((u >> 16) & 1u)) >> 16;
    return (ushortT)r;
}

// ---------------------------------------------------------------------------
// float32 -> bf16 conversion (vectorized)
// ---------------------------------------------------------------------------
__global__ __launch_bounds__(256) void cvt_bf16(const float* __restrict__ src,
                                                ushortT* __restrict__ dst, int n) {
    int i = (blockIdx.x * 256 + threadIdx.x) * 4;
    if (i < n) {
        float4 v = *(const float4*)(src + i);
        ushortT o0 = f2bf(v.x), o1 = f2bf(v.y), o2 = f2bf(v.z), o3 = f2bf(v.w);
        ushort4 pk = make_ushort4(o0, o1, o2, o3);
        *(ushort4*)(dst + i) = pk;
    }
}

// ---------------------------------------------------------------------------
// bf16 MFMA GEMM: C[t,o] = sum_c A[t,c]*B[o,c], M=T rows, N=1024, K=1024.
// 128x128 tile, BK=32, 4 waves, each wave 64x64 (4x4 frags of 16x16x32).
// MODE 0: fp32 out [T][C]    MODE 1: RoPE -> bf16 [h][T][d]
// MODE 2: bf16 V^T [h][d][T]
// ---------------------------------------------------------------------------
template <int MODE>
__global__ __launch_bounds__(256) void gemm_mfma(
    const ushortT* __restrict__ A, const ushortT* __restrict__ B,
    const float* __restrict__ fcos, const float* __restrict__ fsin,
    void* __restrict__ dst)
{
    __shared__ char lds[32768];
    ushortT* As = (ushortT*)lds;            // [128][32] bf16, 8KB
    ushortT* Bs = (ushortT*)(lds + 8192);   // [128][32] bf16, 8KB

    const int bm = blockIdx.x * 128;
    const int bn = blockIdx.y * 128;
    const int tid = threadIdx.x;
    const int w = tid >> 6, l = tid & 63;
    const int wm = w >> 1, wn = w & 1;

    f32x4 acc[4][4] = {};

    for (int kk = 0; kk < CC; kk += 32) {
        #pragma unroll
        for (int e = 0; e < 2; ++e) {
            const int D = (w * 2 + e) * 1024 + l * 16;  // byte in 8KB tile
            const int r = D >> 6;                       // row (64B/row)
            const int c = (D & 63) >> 1;                // bf16 col
            GLOAD_LDS16(A + (size_t)(bm + r) * CC + kk + c, lds + (w * 2 + e) * 1024);
            GLOAD_LDS16(B + (size_t)(bn + r) * CC + kk + c, lds + 8192 + (w * 2 + e) * 1024);
        }
        __syncthreads();
        short8 af[4], bf[4];
        #pragma unroll
        for (int i = 0; i < 4; ++i) {
            int row = wm * 64 + i * 16 + (l & 15);
            af[i] = *(const short8*)(As + row * 32 + (l >> 4) * 8);
        }
        #pragma unroll
        for (int j = 0; j < 4; ++j) {
            int row = wn * 64 + j * 16 + (l & 15);
            bf[j] = *(const short8*)(Bs + row * 32 + (l >> 4) * 8);
        }
        #pragma unroll
        for (int i = 0; i < 4; ++i)
            #pragma unroll
            for (int j = 0; j < 4; ++j)
                acc[i][j] = __builtin_amdgcn_mfma_f32_16x16x32_bf16(af[i], bf[j], acc[i][j], 0, 0, 0);
        __syncthreads();
    }

    if (MODE == 1) {
        // stage cos/sin for this block's 128 t-rows (reuse LDS)
        float* cs = (float*)lds;             // [128][32] 16KB
        float* sn = (float*)(lds + 16384);   // 16KB
        for (int idx = tid; idx < 128 * 32; idx += 256) {
            int rr = idx >> 5, cc2 = idx & 31;
            cs[idx] = fcos[(size_t)(bm + rr) * 32 + cc2];
            sn[idx] = fsin[(size_t)(bm + rr) * 32 + cc2];
        }
        __syncthreads();
        ushortT* dq = (ushortT*)dst;
        #pragma unroll
        for (int i = 0; i < 4; ++i)
            #pragma unroll
            for (int j = 0; j < 4; ++j)
                #pragma unroll
                for (int r = 0; r < 4; ++r) {
                    const int lt = wm * 64 + i * 16 + (l >> 4) * 4 + r;
                    const int o = bn + wn * 64 + j * 16 + (l & 15);
                    const float v = acc[i][j][r];
                    const float p = __shfl_xor(v, 1);
                    const int pp = (o & 63) >> 1;
                    const float cv = cs[lt * 32 + pp], sv = sn[lt * 32 + pp];
                    const float outv = (o & 1) ? (p * sv + v * cv) : (v * cv - p * sv);
                    const int t = bm + lt, head = o >> 6, dd = o & 63;
                    dq[((size_t)head * TT + t) * HD + dd] = f2bf(outv);
                }
    } else if (MODE == 2) {
        ushortT* dv = (ushortT*)dst;
        #pragma unroll
        for (int i = 0; i < 4; ++i)
            #pragma unroll
            for (int j = 0; j < 4; ++j)
                #pragma unroll
                for (int r = 0; r < 4; ++r) {
                    const int t = bm + wm * 64 + i * 16 + (l >> 4) * 4 + r;
                    const int o = bn + wn * 64 + j * 16 + (l & 15);
                    const int head = o >> 6, dd = o & 63;
                    dv[((size_t)(head * HD + dd)) * TT + t] = f2bf(acc[i][j][r]);
                }
    } else {
        float* dout = (float*)dst;
        #pragma unroll
        for (int i = 0; i < 4; ++i)
            #pragma unroll
            for (int j = 0; j < 4; ++j)
                #pragma unroll
                for (int r = 0; r < 4; ++r) {
                    const int t = bm + wm * 64 + i * 16 + (l >> 4) * 4 + r;
                    const int o = bn + wn * 64 + j * 16 + (l & 15);
                    dout[(size_t)t * CC + o] = acc[i][j][r];
                }
    }
}

// ---------------------------------------------------------------------------
// bf16 MFMA flash attention, causal.  Block = (q-block of 64 rows, head),
// 4 waves, each wave owns 16 q-rows.  KV tiles of 64 keys.
// q,k: bf16 [h][T][d]; vt: bf16 [h][d][T]; y out: bf16 [T][C].
// ---------------------------------------------------------------------------
__global__ __launch_bounds__(256) void attn_mfma(
    const ushortT* __restrict__ q16, const ushortT* __restrict__ k16,
    const ushortT* __restrict__ vt16, ushortT* __restrict__ y16)
{
    const int qb = (int)gridDim.x - 1 - (int)blockIdx.x;  // heavy blocks first
    const int head = blockIdx.y;
    const int tid = threadIdx.x;
    const int w = tid >> 6, l = tid & 63;

    __shared__ ushortT lds[12288];          // 24KB
    ushortT* Ks = lds;                      // [64key][64d] swz, 8KB
    ushortT* Vts = lds + 4096;              // [64d][64key] swz, 8KB
    ushortT* Ps = lds + 8192 + w * 1024;    // per-wave [16q][64key] swz, 2KB

    // Q fragments for this wave's 16 rows (row = l&15, k-chunk = l>>4)
    const int qrow = qb * 64 + w * 16 + (l & 15);
    short8 qa[2];
    {
        const ushortT* qp = q16 + ((size_t)head * TT + qrow) * HD + (l >> 4) * 8;
        qa[0] = *(const short8*)(qp);
        qa[1] = *(const short8*)(qp + 32);
    }

    f32x4 yacc[4] = {};          // [d-group]; regs = 4 q rows
    float m_r[4], l_r[4];
    #pragma unroll
    for (int r = 0; r < 4; ++r) { m_r[r] = -1e30f; l_r[r] = 0.0f; }

    const int ntiles = qb + 1;
    for (int kb = 0; kb < ntiles; ++kb) {
        // stage K and Vt tiles (8KB each), XOR-swizzled via source permute
        #pragma unroll
        for (int e = 0; e < 2; ++e) {
            const int D = (w * 2 + e) * 1024 + l * 16;   // dest byte in tile
            const int row = D >> 7;                      // 128B rows
            const int src = D ^ ((row & 7) << 4);        // linear source byte
            const int col = (src & 127) >> 1;            // bf16 col in row
            GLOAD_LDS16(k16 + ((size_t)head * TT + (size_t)kb * 64 + row) * HD + col,
                        (char*)Ks + (w * 2 + e) * 1024);
            GLOAD_LDS16(vt16 + ((size_t)head * HD + row) * TT + (size_t)kb * 64 + col,
                        (char*)Vts + (w * 2 + e) * 1024);
        }
        __syncthreads();

        // S = Q K^T  (A=Q frag, B: col=key=kg*16+(l&15), k=d)
        f32x4 s[4] = {};
        #pragma unroll
        for (int ks = 0; ks < 2; ++ks)
            #pragma unroll
            for (int kg = 0; kg < 4; ++kg) {
                const int key = kg * 16 + (l & 15);
                int b = key * 128 + ks * 64 + (l >> 4) * 16;
                b ^= (key & 7) << 4;
                short8 kf = *(const short8*)((const char*)Ks + b);
                s[kg] = __builtin_amdgcn_mfma_f32_16x16x32_bf16(qa[ks], kf, s[kg], 0, 0, 0);
            }

        // mask + scale
        const int qg = qb * 64 + w * 16 + (l >> 4) * 4;
        #pragma unroll
        for (int kg = 0; kg < 4; ++kg)
            #pragma unroll
            for (int r = 0; r < 4; ++r) {
                float v = s[kg][r] * 0.125f;
                if (kb * 64 + kg * 16 + (l & 15) > qg + r) v = -1e30f;
                s[kg][r] = v;
            }

        // online softmax (rows live in 16-lane groups; shfl_xor 1,2,4,8)
        float alpha[4];
        #pragma unroll
        for (int r = 0; r < 4; ++r) {
            float mx = fmaxf(fmaxf(s[0][r], s[1][r]), fmaxf(s[2][r], s[3][r]));
            mx = fmaxf(mx, __shfl_xor(mx, 1));
            mx = fmaxf(mx, __shfl_xor(mx, 2));
            mx = fmaxf(mx, __shfl_xor(mx, 4));
            mx = fmaxf(mx, __shfl_xor(mx, 8));
            const float mnew = fmaxf(m_r[r], mx);
            alpha[r] = __expf(m_r[r] - mnew);
            m_r[r] = mnew;
            float rs = 0.0f;
            #pragma unroll
            for (int kg = 0; kg < 4; ++kg) {
                float p = __expf(s[kg][r] - mnew);
                s[kg][r] = p;
                rs += p;
            }
            rs += __shfl_xor(rs, 1);
            rs += __shfl_xor(rs, 2);
            rs += __shfl_xor(rs, 4);
            rs += __shfl_xor(rs, 8);
            l_r[r] = l_r[r] * alpha[r] + rs;
        }

        // P -> per-wave LDS (bf16, swizzled)
        #pragma unroll
        for (int kg = 0; kg < 4; ++kg)
            #pragma unroll
            for (int r = 0; r < 4; ++r) {
                const int qq = (l >> 4) * 4 + r;
                int b = qq * 128 + (kg * 16 + (l & 15)) * 2;
                b ^= (qq & 7) << 4;
                *(ushortT*)((char*)Ps + b) = f2bf(s[kg][r]);
            }

        // rescale yacc
        #pragma unroll
        for (int dg = 0; dg < 4; ++dg)
            #pragma unroll
            for (int r = 0; r < 4; ++r)
                yacc[dg][r] *= alpha[r];

        // Y += P V   (A: row=q=l&15, k=key; B: col=d, k=key from Vt)
        #pragma unroll
        for (int ks2 = 0; ks2 < 2; ++ks2) {
            const int qq = l & 15;
            int pb = qq * 128 + ks2 * 64 + (l >> 4) * 16;
            pb ^= (qq & 7) << 4;
            short8 pa = *(const short8*)((const char*)Ps + pb);
            #pragma unroll
            for (int dg = 0; dg < 4; ++dg) {
                const int dd = dg * 16 + (l & 15);
                int vb = dd * 128 + ks2 * 64 + (l >> 4) * 16;
                vb ^= (dd & 7) << 4;
                short8 vf = *(const short8*)((const char*)Vts + vb);
                yacc[dg] = __builtin_amdgcn_mfma_f32_16x16x32_bf16(pa, vf, yacc[dg], 0, 0, 0);
            }
        }
        __syncthreads();
    }

    // write y [T][C] bf16, normalized
    float linv[4];
    #pragma unroll
    for (int r = 0; r < 4; ++r) linv[r] = 1.0f / l_r[r];
    #pragma unroll
    for (int dg = 0; dg < 4; ++dg)
        #pragma unroll
        for (int r = 0; r < 4; ++r) {
            const int t = qb * 64 + w * 16 + (l >> 4) * 4 + r;
            const int c = head * HD + dg * 16 + (l & 15);
            y16[(size_t)t * CC + c] = f2bf(yacc[dg][r] * linv[r]);
        }
}

extern "C" void kernel_launch(void* const* d_in, const int* in_sizes, int n_in,
                              void* d_out, int out_size, void* d_ws, size_t ws_size,
                              hipStream_t stream) {
    const float* x    = (const float*)d_in[0];
    const float* fcos = (const float*)d_in[1];
    const float* fsin = (const float*)d_in[2];
    const float* Wq   = (const float*)d_in[3];
    const float* Wk   = (const float*)d_in[4];
    const float* Wv   = (const float*)d_in[5];
    const float* Wo   = (const float*)d_in[6];
    float* out = (float*)d_out;

    char* ws = (char*)d_ws;
    ushortT* xb  = (ushortT*)(ws);                       // 8MB  [T][C]
    ushortT* wqb = (ushortT*)(ws + (8u << 20));          // 2MB
    ushortT* wkb = (ushortT*)(ws + (10u << 20));
    ushortT* wvb = (ushortT*)(ws + (12u << 20));
    ushortT* wob = (ushortT*)(ws + (14u << 20));
    ushortT* q16 = (ushortT*)(ws + (16u << 20));         // 8MB [h][T][d]
    ushortT* k16 = (ushortT*)(ws + (24u << 20));         // 8MB [h][T][d]
    ushortT* vt16 = (ushortT*)(ws + (32u << 20));        // 8MB [h][d][T]
    ushortT* y16 = (ushortT*)(ws + (40u << 20));         // 8MB [T][C]

    const int nx = TT * CC, nw = CC * CC;
    cvt_bf16<<<nx / 4 / 256, 256, 0, stream>>>(x, xb, nx);
    cvt_bf16<<<nw / 4 / 256, 256, 0, stream>>>(Wq, wqb, nw);
    cvt_bf16<<<nw / 4 / 256, 256, 0, stream>>>(Wk, wkb, nw);
    cvt_bf16<<<nw / 4 / 256, 256, 0, stream>>>(Wv, wvb, nw);
    cvt_bf16<<<nw / 4 / 256, 256, 0, stream>>>(Wo, wob, nw);

    dim3 ggrid(TT / 128, CC / 128);
    gemm_mfma<1><<<ggrid, 256, 0, stream>>>(xb, wqb, fcos, fsin, q16);
    gemm_mfma<1><<<ggrid, 256, 0, stream>>>(xb, wkb, fcos, fsin, k16);
    gemm_mfma<2><<<ggrid, 256, 0, stream>>>(xb, wvb, fcos, fsin, vt16);

    dim3 agrid(TT / 64, NH);
    attn_mfma<<<agrid, 256, 0, stream>>>(q16, k16, vt16, y16);

    gemm_mfma<0><<<ggrid, 256, 0, stream>>>(y16, wob, fcos, fsin, out);
}

// Round 3
// 305.654 us; speedup vs baseline: 7.4554x; 1.0529x over previous
//
#include <hip/hip_runtime.h>
#include <math.h>

#define TT 4096
#define CC 1024
#define NH 16
#define HD 64

typedef unsigned short ushortT;
typedef __attribute__((ext_vector_type(8))) short short8;
typedef __attribute__((ext_vector_type(4))) float f32x4;

#define GLOAD_LDS16(gp, lp)                                                   \
    __builtin_amdgcn_global_load_lds(                                         \
        (const __attribute__((address_space(1))) void*)(gp),                  \
        (__attribute__((address_space(3))) void*)(lp), 16, 0, 0)

__device__ __forceinline__ ushortT f2bf(float f) {
    unsigned u = __float_as_uint(f);
    unsigned r = (u + 0x7FFFu + ((u >> 16) & 1u)) >> 16;
    return (ushortT)r;
}

// ---------------------------------------------------------------------------
// float32 -> bf16 conversion (vectorized)
// ---------------------------------------------------------------------------
__global__ __launch_bounds__(256) void cvt_bf16(const float* __restrict__ src,
                                                ushortT* __restrict__ dst, int n) {
    int i = (blockIdx.x * 256 + threadIdx.x) * 4;
    if (i < n) {
        float4 v = *(const float4*)(src + i);
        *(ushort4*)(dst + i) = make_ushort4(f2bf(v.x), f2bf(v.y), f2bf(v.z), f2bf(v.w));
    }
}

// ---------------------------------------------------------------------------
// bf16 MFMA GEMM: C[t,o] = sum_c A[t,c]*B[o,c].  128x128 tile, BK=32, 4 waves.
// MODE 0: fp32 out [T][C]
// MODE 1: RoPE -> bf16 [h][T][d]                       (K)
// MODE 3: RoPE, scaled by 0.125*log2(e) -> bf16 [h][T][d]  (Q)
// MODE 2: bf16 V^T [h][d][T]
// ---------------------------------------------------------------------------
template <int MODE>
__global__ __launch_bounds__(256) void gemm_mfma(
    const ushortT* __restrict__ A, const ushortT* __restrict__ B,
    const float* __restrict__ fcos, const float* __restrict__ fsin,
    void* __restrict__ dst)
{
    __shared__ char lds[32768];
    ushortT* As = (ushortT*)lds;            // [128][32] bf16, 8KB
    ushortT* Bs = (ushortT*)(lds + 8192);   // [128][32] bf16, 8KB

    const int bm = blockIdx.x * 128;
    const int bn = blockIdx.y * 128;
    const int tid = threadIdx.x;
    const int w = tid >> 6, l = tid & 63;
    const int wm = w >> 1, wn = w & 1;

    f32x4 acc[4][4] = {};

    for (int kk = 0; kk < CC; kk += 32) {
        #pragma unroll
        for (int e = 0; e < 2; ++e) {
            const int D = (w * 2 + e) * 1024 + l * 16;
            const int r = D >> 6;
            const int c = (D & 63) >> 1;
            GLOAD_LDS16(A + (size_t)(bm + r) * CC + kk + c, lds + (w * 2 + e) * 1024);
            GLOAD_LDS16(B + (size_t)(bn + r) * CC + kk + c, lds + 8192 + (w * 2 + e) * 1024);
        }
        __syncthreads();
        short8 af[4], bfr[4];
        #pragma unroll
        for (int i = 0; i < 4; ++i) {
            int row = wm * 64 + i * 16 + (l & 15);
            af[i] = *(const short8*)(As + row * 32 + (l >> 4) * 8);
        }
        #pragma unroll
        for (int j = 0; j < 4; ++j) {
            int row = wn * 64 + j * 16 + (l & 15);
            bfr[j] = *(const short8*)(Bs + row * 32 + (l >> 4) * 8);
        }
        #pragma unroll
        for (int i = 0; i < 4; ++i)
            #pragma unroll
            for (int j = 0; j < 4; ++j)
                acc[i][j] = __builtin_amdgcn_mfma_f32_16x16x32_bf16(af[i], bfr[j], acc[i][j], 0, 0, 0);
        __syncthreads();
    }

    if (MODE == 1 || MODE == 3) {
        const float rsc = (MODE == 3) ? 0.18033688011112042f : 1.0f;  // 0.125*log2(e)
        float* cs = (float*)lds;
        float* sn = (float*)(lds + 16384);
        for (int idx = tid; idx < 128 * 32; idx += 256) {
            int rr = idx >> 5, cc2 = idx & 31;
            cs[idx] = fcos[(size_t)(bm + rr) * 32 + cc2];
            sn[idx] = fsin[(size_t)(bm + rr) * 32 + cc2];
        }
        __syncthreads();
        ushortT* dq = (ushortT*)dst;
        #pragma unroll
        for (int i = 0; i < 4; ++i)
            #pragma unroll
            for (int j = 0; j < 4; ++j)
                #pragma unroll
                for (int r = 0; r < 4; ++r) {
                    const int lt = wm * 64 + i * 16 + (l >> 4) * 4 + r;
                    const int o = bn + wn * 64 + j * 16 + (l & 15);
                    const float v = acc[i][j][r];
                    const float p = __shfl_xor(v, 1);
                    const int pp = (o & 63) >> 1;
                    const float cv = cs[lt * 32 + pp], sv = sn[lt * 32 + pp];
                    const float outv = ((o & 1) ? (p * sv + v * cv) : (v * cv - p * sv)) * rsc;
                    const int t = bm + lt, head = o >> 6, dd = o & 63;
                    dq[((size_t)head * TT + t) * HD + dd] = f2bf(outv);
                }
    } else if (MODE == 2) {
        ushortT* dv = (ushortT*)dst;
        #pragma unroll
        for (int i = 0; i < 4; ++i)
            #pragma unroll
            for (int j = 0; j < 4; ++j)
                #pragma unroll
                for (int r = 0; r < 4; ++r) {
                    const int t = bm + wm * 64 + i * 16 + (l >> 4) * 4 + r;
                    const int o = bn + wn * 64 + j * 16 + (l & 15);
                    const int head = o >> 6, dd = o & 63;
                    dv[((size_t)(head * HD + dd)) * TT + t] = f2bf(acc[i][j][r]);
                }
    } else {
        float* dout = (float*)dst;
        #pragma unroll
        for (int i = 0; i < 4; ++i)
            #pragma unroll
            for (int j = 0; j < 4; ++j)
                #pragma unroll
                for (int r = 0; r < 4; ++r) {
                    const int t = bm + wm * 64 + i * 16 + (l >> 4) * 4 + r;
                    const int o = bn + wn * 64 + j * 16 + (l & 15);
                    dout[(size_t)t * CC + o] = acc[i][j][r];
                }
    }
}

// ---------------------------------------------------------------------------
// bf16 MFMA flash attention, causal, 2-phase prefetch double-buffer.
// Block = (64 q-rows, head), 4 waves x 16 q-rows.  64-key tiles.
// Q is pre-scaled by 0.125*log2(e) -> softmax in exp2 domain.
// q,k: bf16 [h][T][d]; vt: bf16 [h][d][T]; y: bf16 [T][C].
// ---------------------------------------------------------------------------
__global__ __launch_bounds__(256) void attn_mfma(
    const ushortT* __restrict__ q16, const ushortT* __restrict__ k16,
    const ushortT* __restrict__ vt16, ushortT* __restrict__ y16)
{
    const int qb = (int)gridDim.x - 1 - (int)blockIdx.x;  // heavy blocks first
    const int head = blockIdx.y;
    const int tid = threadIdx.x;
    const int w = tid >> 6, l = tid & 63;

    // LDS: 2 x (K 8KB + Vt 8KB) + P 4x2KB = 40KB
    __shared__ char lds[40960];
    char* Pbase = lds + 32768 + w * 2048;   // per-wave [16q][64key] bf16 swz

    // Q fragments (row = l&15, k-chunk = l>>4)
    const int qrow = qb * 64 + w * 16 + (l & 15);
    short8 qa[2];
    {
        const ushortT* qp = q16 + ((size_t)head * TT + qrow) * HD + (l >> 4) * 8;
        qa[0] = *(const short8*)(qp);
        qa[1] = *(const short8*)(qp + 32);
    }

    f32x4 yacc[4] = {};
    float m_r[4], l_r[4];
    #pragma unroll
    for (int r = 0; r < 4; ++r) { m_r[r] = -1e30f; l_r[r] = 0.0f; }

    auto stage = [&](int kb, int base) {
        #pragma unroll
        for (int e = 0; e < 2; ++e) {
            const int D = (w * 2 + e) * 1024 + l * 16;
            const int row = D >> 7;
            const int src = D ^ ((row & 7) << 4);
            const int col = (src & 127) >> 1;
            GLOAD_LDS16(k16 + ((size_t)head * TT + (size_t)kb * 64 + row) * HD + col,
                        lds + base + (w * 2 + e) * 1024);
            GLOAD_LDS16(vt16 + ((size_t)head * HD + row) * TT + (size_t)kb * 64 + col,
                        lds + base + 8192 + (w * 2 + e) * 1024);
        }
    };

    const int ntiles = qb + 1;
    int cur = 0;
    stage(0, 0);
    __syncthreads();

    for (int kb = 0; kb < ntiles; ++kb) {
        if (kb + 1 < ntiles) stage(kb + 1, (cur ^ 1) * 16384);
        const char* Ks  = lds + cur * 16384;
        const char* Vts = Ks + 8192;

        // S = Q K^T  (values already in exp2 domain)
        f32x4 s[4] = {};
        #pragma unroll
        for (int ks = 0; ks < 2; ++ks)
            #pragma unroll
            for (int kg = 0; kg < 4; ++kg) {
                const int key = kg * 16 + (l & 15);
                int b = key * 128 + ks * 64 + (l >> 4) * 16;
                b ^= (key & 7) << 4;
                short8 kf = *(const short8*)(Ks + b);
                s[kg] = __builtin_amdgcn_mfma_f32_16x16x32_bf16(qa[ks], kf, s[kg], 0, 0, 0);
            }

        // causal mask: only the diagonal tile needs it
        if (kb == qb) {
            const int qg = qb * 64 + w * 16 + (l >> 4) * 4;
            #pragma unroll
            for (int kg = 0; kg < 4; ++kg)
                #pragma unroll
                for (int r = 0; r < 4; ++r)
                    if (kb * 64 + kg * 16 + (l & 15) > qg + r) s[kg][r] = -1e30f;
        }

        // online softmax: cross-lane max, in-lane exp2/partial-sum (l deferred)
        float alpha[4];
        #pragma unroll
        for (int r = 0; r < 4; ++r) {
            float mx = fmaxf(fmaxf(s[0][r], s[1][r]), fmaxf(s[2][r], s[3][r]));
            mx = fmaxf(mx, __shfl_xor(mx, 1));
            mx = fmaxf(mx, __shfl_xor(mx, 2));
            mx = fmaxf(mx, __shfl_xor(mx, 4));
            mx = fmaxf(mx, __shfl_xor(mx, 8));
            const float mnew = fmaxf(m_r[r], mx);
            alpha[r] = exp2f(m_r[r] - mnew);
            m_r[r] = mnew;
            float ls = 0.0f;
            #pragma unroll
            for (int kg = 0; kg < 4; ++kg) {
                float p = exp2f(s[kg][r] - mnew);
                s[kg][r] = p;
                ls += p;
            }
            l_r[r] = l_r[r] * alpha[r] + ls;
        }

        // P -> per-wave LDS (bf16, swizzled)
        #pragma unroll
        for (int kg = 0; kg < 4; ++kg)
            #pragma unroll
            for (int r = 0; r < 4; ++r) {
                const int qq = (l >> 4) * 4 + r;
                int b = qq * 128 + (kg * 16 + (l & 15)) * 2;
                b ^= (qq & 7) << 4;
                *(ushortT*)(Pbase + b) = f2bf(s[kg][r]);
            }

        #pragma unroll
        for (int dg = 0; dg < 4; ++dg)
            #pragma unroll
            for (int r = 0; r < 4; ++r)
                yacc[dg][r] *= alpha[r];

        // Y += P V
        #pragma unroll
        for (int ks2 = 0; ks2 < 2; ++ks2) {
            const int qq = l & 15;
            int pb = qq * 128 + ks2 * 64 + (l >> 4) * 16;
            pb ^= (qq & 7) << 4;
            short8 pa = *(const short8*)(Pbase + pb);
            #pragma unroll
            for (int dg = 0; dg < 4; ++dg) {
                const int dd = dg * 16 + (l & 15);
                int vb = dd * 128 + ks2 * 64 + (l >> 4) * 16;
                vb ^= (dd & 7) << 4;
                short8 vf = *(const short8*)(Vts + vb);
                yacc[dg] = __builtin_amdgcn_mfma_f32_16x16x32_bf16(pa, vf, yacc[dg], 0, 0, 0);
            }
        }
        __syncthreads();
        cur ^= 1;
    }

    // final cross-lane reduce of deferred row sums, then write y
    float linv[4];
    #pragma unroll
    for (int r = 0; r < 4; ++r) {
        float t = l_r[r];
        t += __shfl_xor(t, 1);
        t += __shfl_xor(t, 2);
        t += __shfl_xor(t, 4);
        t += __shfl_xor(t, 8);
        linv[r] = 1.0f / t;
    }
    #pragma unroll
    for (int dg = 0; dg < 4; ++dg)
        #pragma unroll
        for (int r = 0; r < 4; ++r) {
            const int t = qb * 64 + w * 16 + (l >> 4) * 4 + r;
            const int c = head * HD + dg * 16 + (l & 15);
            y16[(size_t)t * CC + c] = f2bf(yacc[dg][r] * linv[r]);
        }
}

extern "C" void kernel_launch(void* const* d_in, const int* in_sizes, int n_in,
                              void* d_out, int out_size, void* d_ws, size_t ws_size,
                              hipStream_t stream) {
    const float* x    = (const float*)d_in[0];
    const float* fcos = (const float*)d_in[1];
    const float* fsin = (const float*)d_in[2];
    const float* Wq   = (const float*)d_in[3];
    const float* Wk   = (const float*)d_in[4];
    const float* Wv   = (const float*)d_in[5];
    const float* Wo   = (const float*)d_in[6];
    float* out = (float*)d_out;

    char* ws = (char*)d_ws;
    ushortT* xb  = (ushortT*)(ws);
    ushortT* wqb = (ushortT*)(ws + (8u << 20));
    ushortT* wkb = (ushortT*)(ws + (10u << 20));
    ushortT* wvb = (ushortT*)(ws + (12u << 20));
    ushortT* wob = (ushortT*)(ws + (14u << 20));
    ushortT* q16 = (ushortT*)(ws + (16u << 20));
    ushortT* k16 = (ushortT*)(ws + (24u << 20));
    ushortT* vt16 = (ushortT*)(ws + (32u << 20));
    ushortT* y16 = (ushortT*)(ws + (40u << 20));

    const int nx = TT * CC, nw = CC * CC;
    cvt_bf16<<<nx / 4 / 256, 256, 0, stream>>>(x, xb, nx);
    cvt_bf16<<<nw / 4 / 256, 256, 0, stream>>>(Wq, wqb, nw);
    cvt_bf16<<<nw / 4 / 256, 256, 0, stream>>>(Wk, wkb, nw);
    cvt_bf16<<<nw / 4 / 256, 256, 0, stream>>>(Wv, wvb, nw);
    cvt_bf16<<<nw / 4 / 256, 256, 0, stream>>>(Wo, wob, nw);

    dim3 ggrid(TT / 128, CC / 128);
    gemm_mfma<3><<<ggrid, 256, 0, stream>>>(xb, wqb, fcos, fsin, q16);
    gemm_mfma<1><<<ggrid, 256, 0, stream>>>(xb, wkb, fcos, fsin, k16);
    gemm_mfma<2><<<ggrid, 256, 0, stream>>>(xb, wvb, fcos, fsin, vt16);

    dim3 agrid(TT / 64, NH);
    attn_mfma<<<agrid, 256, 0, stream>>>(q16, k16, vt16, y16);

    gemm_mfma<0><<<ggrid, 256, 0, stream>>>(y16, wob, fcos, fsin, out);
}

// Round 5
// 258.471 us; speedup vs baseline: 8.8164x; 1.1825x over previous
//
#include <hip/hip_runtime.h>
#include <hip/hip_bf16.h>
#include <math.h>

#define TT 4096
#define CC 1024
#define NH 16
#define HD 64

typedef unsigned short ushortT;
typedef __attribute__((ext_vector_type(8))) short short8;
typedef __attribute__((ext_vector_type(4))) float f32x4;

#define GLOAD_LDS16(gp, lp)                                                   \
    __builtin_amdgcn_global_load_lds(                                         \
        (const __attribute__((address_space(1))) void*)(gp),                  \
        (__attribute__((address_space(3))) void*)(lp), 16, 0, 0)

__device__ __forceinline__ ushortT f2bf(float f) {
    __hip_bfloat16 h = __float2bfloat16(f);
    ushortT u; __builtin_memcpy(&u, &h, 2); return u;
}

// Partial-attention slot (f32): y[64][64] + m[64] + l[64] = 16384+256+256
#define PSLOT_BYTES 16896
#define QB_SPLIT 40   // qb >= QB_SPLIT uses 2 chunks; 16*24*2*16896 = 12.98MB < 14MB

// ---------------------------------------------------------------------------
__global__ __launch_bounds__(256) void cvt_bf16(const float* __restrict__ src,
                                                ushortT* __restrict__ dst, int n) {
    int i = (blockIdx.x * 256 + threadIdx.x) * 4;
    if (i < n) {
        float4 v = *(const float4*)(src + i);
        *(ushort4*)(dst + i) = make_ushort4(f2bf(v.x), f2bf(v.y), f2bf(v.z), f2bf(v.w));
    }
}

// ---------------------------------------------------------------------------
// bf16 MFMA GEMM: C[t,o] = sum_c A[t,c]*B[o,c].  128x128 tile, BK=32, 4 waves.
// MODE 0: fp32 out [T][C]
// MODE 1: RoPE -> bf16 [h][T][d]                          (K)
// MODE 3: RoPE scaled by 0.125*log2(e) -> bf16 [h][T][d]  (Q)
// MODE 2: bf16 V^T [h][d][T]
// ---------------------------------------------------------------------------
template <int MODE>
__global__ __launch_bounds__(256) void gemm_mfma(
    const ushortT* __restrict__ A, const ushortT* __restrict__ B,
    const float* __restrict__ fcos, const float* __restrict__ fsin,
    void* __restrict__ dst)
{
    __shared__ char lds[32768];
    ushortT* As = (ushortT*)lds;
    ushortT* Bs = (ushortT*)(lds + 8192);

    const int bm = blockIdx.x * 128;
    const int bn = blockIdx.y * 128;
    const int tid = threadIdx.x;
    const int w = tid >> 6, l = tid & 63;
    const int wm = w >> 1, wn = w & 1;

    f32x4 acc[4][4] = {};

    for (int kk = 0; kk < CC; kk += 32) {
        #pragma unroll
        for (int e = 0; e < 2; ++e) {
            const int D = (w * 2 + e) * 1024 + l * 16;
            const int r = D >> 6;
            const int c = (D & 63) >> 1;
            GLOAD_LDS16(A + (size_t)(bm + r) * CC + kk + c, lds + (w * 2 + e) * 1024);
            GLOAD_LDS16(B + (size_t)(bn + r) * CC + kk + c, lds + 8192 + (w * 2 + e) * 1024);
        }
        __syncthreads();
        short8 af[4], bfr[4];
        #pragma unroll
        for (int i = 0; i < 4; ++i) {
            int row = wm * 64 + i * 16 + (l & 15);
            af[i] = *(const short8*)(As + row * 32 + (l >> 4) * 8);
        }
        #pragma unroll
        for (int j = 0; j < 4; ++j) {
            int row = wn * 64 + j * 16 + (l & 15);
            bfr[j] = *(const short8*)(Bs + row * 32 + (l >> 4) * 8);
        }
        #pragma unroll
        for (int i = 0; i < 4; ++i)
            #pragma unroll
            for (int j = 0; j < 4; ++j)
                acc[i][j] = __builtin_amdgcn_mfma_f32_16x16x32_bf16(af[i], bfr[j], acc[i][j], 0, 0, 0);
        __syncthreads();
    }

    if (MODE == 1 || MODE == 3) {
        const float rsc = (MODE == 3) ? 0.18033688011112042f : 1.0f;  // 0.125*log2(e)
        float* cs = (float*)lds;
        float* sn = (float*)(lds + 16384);
        for (int idx = tid; idx < 128 * 32; idx += 256) {
            int rr = idx >> 5, cc2 = idx & 31;
            cs[idx] = fcos[(size_t)(bm + rr) * 32 + cc2];
            sn[idx] = fsin[(size_t)(bm + rr) * 32 + cc2];
        }
        __syncthreads();
        ushortT* dq = (ushortT*)dst;
        #pragma unroll
        for (int i = 0; i < 4; ++i)
            #pragma unroll
            for (int j = 0; j < 4; ++j)
                #pragma unroll
                for (int r = 0; r < 4; ++r) {
                    const int lt = wm * 64 + i * 16 + (l >> 4) * 4 + r;
                    const int o = bn + wn * 64 + j * 16 + (l & 15);
                    const float v = acc[i][j][r];
                    const float p = __shfl_xor(v, 1);
                    const int pp = (o & 63) >> 1;
                    const float cv = cs[lt * 32 + pp], sv = sn[lt * 32 + pp];
                    const float outv = ((o & 1) ? (p * sv + v * cv) : (v * cv - p * sv)) * rsc;
                    const int t = bm + lt, head = o >> 6, dd = o & 63;
                    dq[((size_t)head * TT + t) * HD + dd] = f2bf(outv);
                }
    } else if (MODE == 2) {
        ushortT* dv = (ushortT*)dst;
        #pragma unroll
        for (int i = 0; i < 4; ++i)
            #pragma unroll
            for (int j = 0; j < 4; ++j)
                #pragma unroll
                for (int r = 0; r < 4; ++r) {
                    const int t = bm + wm * 64 + i * 16 + (l >> 4) * 4 + r;
                    const int o = bn + wn * 64 + j * 16 + (l & 15);
                    const int head = o >> 6, dd = o & 63;
                    dv[((size_t)(head * HD + dd)) * TT + t] = f2bf(acc[i][j][r]);
                }
    } else {
        float* dout = (float*)dst;
        #pragma unroll
        for (int i = 0; i < 4; ++i)
            #pragma unroll
            for (int j = 0; j < 4; ++j)
                #pragma unroll
                for (int r = 0; r < 4; ++r) {
                    const int t = bm + wm * 64 + i * 16 + (l >> 4) * 4 + r;
                    const int o = bn + wn * 64 + j * 16 + (l & 15);
                    dout[(size_t)t * CC + o] = acc[i][j][r];
                }
    }
}

// ---------------------------------------------------------------------------
// bf16 MFMA flash attention, causal, split-KV for load balance.
// 88 chunks/head: cid<40 -> qb=cid, full range, direct y16 write;
// cid>=40 -> qb=40+(idx>>1), half-range chunk, f32 partial (y,m,l).
// Heavy chunks launch first (cid = 87 - blockIdx.x).
// ---------------------------------------------------------------------------
__global__ __launch_bounds__(256) void attn_mfma(
    const ushortT* __restrict__ q16, const ushortT* __restrict__ k16,
    const ushortT* __restrict__ vt16, ushortT* __restrict__ y16,
    char* __restrict__ parts)
{
    const int cid = 87 - (int)blockIdx.x;
    const int head = blockIdx.y;
    int qb, ci, kb0, kb1;
    if (cid < QB_SPLIT) { qb = cid; ci = -1; kb0 = 0; kb1 = qb; }
    else {
        const int idx = cid - QB_SPLIT;
        qb = QB_SPLIT + (idx >> 1);
        ci = idx & 1;
        const int mid = (qb + 1) >> 1;
        kb0 = ci ? mid : 0;
        kb1 = ci ? qb : mid - 1;
    }

    const int tid = threadIdx.x;
    const int w = tid >> 6, l = tid & 63;

    __shared__ char lds[40960];            // 2 x (K 8KB + Vt 8KB) + P 4x2KB
    char* Pbase = lds + 32768 + w * 2048;

    const int qrow = qb * 64 + w * 16 + (l & 15);
    short8 qa[2];
    {
        const ushortT* qp = q16 + ((size_t)head * TT + qrow) * HD + (l >> 4) * 8;
        qa[0] = *(const short8*)(qp);
        qa[1] = *(const short8*)(qp + 32);
    }

    f32x4 yacc[4] = {};
    float m_r[4], l_r[4];
    #pragma unroll
    for (int r = 0; r < 4; ++r) { m_r[r] = -1e30f; l_r[r] = 0.0f; }

    auto stage = [&](int kb, int base) {
        #pragma unroll
        for (int e = 0; e < 2; ++e) {
            const int D = (w * 2 + e) * 1024 + l * 16;
            const int row = D >> 7;
            const int src = D ^ ((row & 7) << 4);
            const int col = (src & 127) >> 1;
            GLOAD_LDS16(k16 + ((size_t)head * TT + (size_t)kb * 64 + row) * HD + col,
                        lds + base + (w * 2 + e) * 1024);
            GLOAD_LDS16(vt16 + ((size_t)head * HD + row) * TT + (size_t)kb * 64 + col,
                        lds + base + 8192 + (w * 2 + e) * 1024);
        }
    };

    int cur = 0;
    stage(kb0, 0);
    __syncthreads();

    for (int kb = kb0; kb <= kb1; ++kb) {
        if (kb + 1 <= kb1) stage(kb + 1, (cur ^ 1) * 16384);
        const char* Ks  = lds + cur * 16384;
        const char* Vts = Ks + 8192;

        f32x4 s[4] = {};
        #pragma unroll
        for (int ks = 0; ks < 2; ++ks)
            #pragma unroll
            for (int kg = 0; kg < 4; ++kg) {
                const int key = kg * 16 + (l & 15);
                int b = key * 128 + ks * 64 + (l >> 4) * 16;
                b ^= (key & 7) << 4;
                short8 kf = *(const short8*)(Ks + b);
                s[kg] = __builtin_amdgcn_mfma_f32_16x16x32_bf16(qa[ks], kf, s[kg], 0, 0, 0);
            }

        if (kb == qb) {   // diagonal tile only
            const int qg = qb * 64 + w * 16 + (l >> 4) * 4;
            #pragma unroll
            for (int kg = 0; kg < 4; ++kg)
                #pragma unroll
                for (int r = 0; r < 4; ++r)
                    if (kb * 64 + kg * 16 + (l & 15) > qg + r) s[kg][r] = -1e30f;
        }

        // tile max (cross-lane within 16-lane row groups)
        float mx[4];
        bool need = false;
        #pragma unroll
        for (int r = 0; r < 4; ++r) {
            float m0 = fmaxf(fmaxf(s[0][r], s[1][r]), fmaxf(s[2][r], s[3][r]));
            m0 = fmaxf(m0, __shfl_xor(m0, 1));
            m0 = fmaxf(m0, __shfl_xor(m0, 2));
            m0 = fmaxf(m0, __shfl_xor(m0, 4));
            m0 = fmaxf(m0, __shfl_xor(m0, 8));
            mx[r] = m0;
            need = need || (m0 - m_r[r] > 8.0f);
        }
        // defer-max: rescale only when some row grew by > 8 (exp2 domain)
        if (__any(need)) {
            #pragma unroll
            for (int r = 0; r < 4; ++r) {
                const float mnew = fmaxf(m_r[r], mx[r]);
                const float al = exp2f(m_r[r] - mnew);
                m_r[r] = mnew;
                l_r[r] *= al;
                #pragma unroll
                for (int dg = 0; dg < 4; ++dg)
                    yacc[dg][r] *= al;
            }
        }
        // P = exp2(s - m), partial row sums (cross-lane reduce deferred)
        #pragma unroll
        for (int r = 0; r < 4; ++r) {
            float ls = 0.0f;
            #pragma unroll
            for (int kg = 0; kg < 4; ++kg) {
                float p = exp2f(s[kg][r] - m_r[r]);
                s[kg][r] = p;
                ls += p;
            }
            l_r[r] += ls;
        }

        #pragma unroll
        for (int kg = 0; kg < 4; ++kg)
            #pragma unroll
            for (int r = 0; r < 4; ++r) {
                const int qq = (l >> 4) * 4 + r;
                int b = qq * 128 + (kg * 16 + (l & 15)) * 2;
                b ^= (qq & 7) << 4;
                *(ushortT*)(Pbase + b) = f2bf(s[kg][r]);
            }

        #pragma unroll
        for (int ks2 = 0; ks2 < 2; ++ks2) {
            const int qq = l & 15;
            int pb = qq * 128 + ks2 * 64 + (l >> 4) * 16;
            pb ^= (qq & 7) << 4;
            short8 pa = *(const short8*)(Pbase + pb);
            #pragma unroll
            for (int dg = 0; dg < 4; ++dg) {
                const int dd = dg * 16 + (l & 15);
                int vb = dd * 128 + ks2 * 64 + (l >> 4) * 16;
                vb ^= (dd & 7) << 4;
                short8 vf = *(const short8*)(Vts + vb);
                yacc[dg] = __builtin_amdgcn_mfma_f32_16x16x32_bf16(pa, vf, yacc[dg], 0, 0, 0);
            }
        }
        __syncthreads();
        cur ^= 1;
    }

    // reduce deferred row-sums across the 16-lane group
    float lsum[4];
    #pragma unroll
    for (int r = 0; r < 4; ++r) {
        float t = l_r[r];
        t += __shfl_xor(t, 1);
        t += __shfl_xor(t, 2);
        t += __shfl_xor(t, 4);
        t += __shfl_xor(t, 8);
        lsum[r] = t;
    }

    if (ci < 0) {
        #pragma unroll
        for (int dg = 0; dg < 4; ++dg)
            #pragma unroll
            for (int r = 0; r < 4; ++r) {
                const int t = qb * 64 + w * 16 + (l >> 4) * 4 + r;
                const int c = head * HD + dg * 16 + (l & 15);
                y16[(size_t)t * CC + c] = f2bf(yacc[dg][r] / lsum[r]);
            }
    } else {
        char* pb = parts + (size_t)((head * 24 + (qb - QB_SPLIT)) * 2 + ci) * PSLOT_BYTES;
        float* yp = (float*)pb;
        float* mp = (float*)(pb + 16384);
        float* lp = mp + 64;
        #pragma unroll
        for (int dg = 0; dg < 4; ++dg)
            #pragma unroll
            for (int r = 0; r < 4; ++r) {
                const int row = w * 16 + (l >> 4) * 4 + r;
                const int col = dg * 16 + (l & 15);
                yp[row * 64 + col] = yacc[dg][r];
            }
        if ((l & 15) == 0) {
            #pragma unroll
            for (int r = 0; r < 4; ++r) {
                const int row = w * 16 + (l >> 4) * 4 + r;
                mp[row] = m_r[r];
                lp[row] = lsum[r];
            }
        }
    }
}

// ---------------------------------------------------------------------------
// Merge the two partial chunks for qb in [QB_SPLIT, 64).
// ---------------------------------------------------------------------------
__global__ __launch_bounds__(256) void attn_combine(
    const char* __restrict__ parts, ushortT* __restrict__ y16)
{
    const int qb = QB_SPLIT + blockIdx.x;
    const int head = blockIdx.y;
    const int tid = threadIdx.x;
    const int row = tid >> 2;
    const int pc = tid & 3;

    const char* p0 = parts + (size_t)((head * 24 + (qb - QB_SPLIT)) * 2) * PSLOT_BYTES;
    const char* p1 = p0 + PSLOT_BYTES;
    const float* y0 = (const float*)p0;
    const float* y1 = (const float*)p1;
    const float* m0p = (const float*)(p0 + 16384);
    const float* m1p = (const float*)(p1 + 16384);
    const float m0 = m0p[row], m1 = m1p[row];
    const float l0 = m0p[64 + row], l1 = m1p[64 + row];
    const float M = fmaxf(m0, m1);
    const float w0 = exp2f(m0 - M), w1 = exp2f(m1 - M);
    const float Linv = 1.0f / (l0 * w0 + l1 * w1);

    const int t = qb * 64 + row;
    #pragma unroll
    for (int j = 0; j < 16; ++j) {
        const int c = pc * 16 + j;
        const float v = (y0[row * 64 + c] * w0 + y1[row * 64 + c] * w1) * Linv;
        y16[(size_t)t * CC + head * HD + c] = f2bf(v);
    }
}

extern "C" void kernel_launch(void* const* d_in, const int* in_sizes, int n_in,
                              void* d_out, int out_size, void* d_ws, size_t ws_size,
                              hipStream_t stream) {
    const float* x    = (const float*)d_in[0];
    const float* fcos = (const float*)d_in[1];
    const float* fsin = (const float*)d_in[2];
    const float* Wq   = (const float*)d_in[3];
    const float* Wk   = (const float*)d_in[4];
    const float* Wv   = (const float*)d_in[5];
    const float* Wo   = (const float*)d_in[6];
    float* out = (float*)d_out;

    char* ws = (char*)d_ws;
    ushortT* xb  = (ushortT*)(ws);                 // [0,8MB)  dead after QKV GEMMs
    ushortT* wqb = (ushortT*)(ws + (8u << 20));    // [8,10MB) dead after Q GEMM
    ushortT* wkb = (ushortT*)(ws + (10u << 20));
    ushortT* wvb = (ushortT*)(ws + (12u << 20));
    ushortT* wob = (ushortT*)(ws + (14u << 20));   // LIVE until final GEMM
    ushortT* q16 = (ushortT*)(ws + (16u << 20));
    ushortT* k16 = (ushortT*)(ws + (24u << 20));
    ushortT* vt16 = (ushortT*)(ws + (32u << 20));
    ushortT* y16 = (ushortT*)(ws + (40u << 20));
    char* parts = ws;   // [0, 12.98MB) — only overlaps dead xb/wqb/wkb regions

    const int nx = TT * CC, nw = CC * CC;
    cvt_bf16<<<nx / 4 / 256, 256, 0, stream>>>(x, xb, nx);
    cvt_bf16<<<nw / 4 / 256, 256, 0, stream>>>(Wq, wqb, nw);
    cvt_bf16<<<nw / 4 / 256, 256, 0, stream>>>(Wk, wkb, nw);
    cvt_bf16<<<nw / 4 / 256, 256, 0, stream>>>(Wv, wvb, nw);
    cvt_bf16<<<nw / 4 / 256, 256, 0, stream>>>(Wo, wob, nw);

    dim3 ggrid(TT / 128, CC / 128);
    gemm_mfma<3><<<ggrid, 256, 0, stream>>>(xb, wqb, fcos, fsin, q16);
    gemm_mfma<1><<<ggrid, 256, 0, stream>>>(xb, wkb, fcos, fsin, k16);
    gemm_mfma<2><<<ggrid, 256, 0, stream>>>(xb, wvb, fcos, fsin, vt16);

    dim3 agrid(88, NH);
    attn_mfma<<<agrid, 256, 0, stream>>>(q16, k16, vt16, y16, parts);

    dim3 cgrid(64 - QB_SPLIT, NH);
    attn_combine<<<cgrid, 256, 0, stream>>>(parts, y16);

    gemm_mfma<0><<<ggrid, 256, 0, stream>>>(y16, wob, fcos, fsin, out);
}

// Round 6
// 241.381 us; speedup vs baseline: 9.4406x; 1.0708x over previous
//
#include <hip/hip_runtime.h>
#include <hip/hip_bf16.h>
#include <math.h>

#define TT 4096
#define CC 1024
#define NH 16
#define HD 64

typedef unsigned short ushortT;
typedef __attribute__((ext_vector_type(8))) short short8;
typedef __attribute__((ext_vector_type(4))) float f32x4;

#define GLOAD_LDS16(gp, lp)                                                   \
    __builtin_amdgcn_global_load_lds(                                         \
        (const __attribute__((address_space(1))) void*)(gp),                  \
        (__attribute__((address_space(3))) void*)(lp), 16, 0, 0)

#define EXP2F(x) __builtin_amdgcn_exp2f(x)   // single v_exp_f32

__device__ __forceinline__ ushortT f2bf(float f) {
    __hip_bfloat16 h = __float2bfloat16(f);
    ushortT u; __builtin_memcpy(&u, &h, 2); return u;
}

// Partial-attention slot (f32): y[64][64] + m[64] + l[64] = 16384+256+256
#define PSLOT_BYTES 16896
#define QB_SPLIT 40   // qb >= QB_SPLIT uses 2 chunks; 16*24*2*16896 = 12.98MB < 14MB

// ---------------------------------------------------------------------------
__global__ __launch_bounds__(256) void cvt_bf16(const float* __restrict__ src,
                                                ushortT* __restrict__ dst, int n) {
    int i = (blockIdx.x * 256 + threadIdx.x) * 4;
    if (i < n) {
        float4 v = *(const float4*)(src + i);
        *(ushort4*)(dst + i) = make_ushort4(f2bf(v.x), f2bf(v.y), f2bf(v.z), f2bf(v.w));
    }
}

// ---------------------------------------------------------------------------
// bf16 MFMA GEMM: C[t,o] = sum_c A[t,c]*B[o,c].  128x128 tile, BK=32, 4 waves.
// MODE 0: fp32 out [T][C]
// MODE 1: RoPE -> bf16 [h][T][d]                          (K)
// MODE 3: RoPE scaled by 0.125*log2(e) -> bf16 [h][T][d]  (Q)
// MODE 2: bf16 V^T [h][d][T]
// ---------------------------------------------------------------------------
template <int MODE>
__global__ __launch_bounds__(256) void gemm_mfma(
    const ushortT* __restrict__ A, const ushortT* __restrict__ B,
    const float* __restrict__ fcos, const float* __restrict__ fsin,
    void* __restrict__ dst)
{
    __shared__ char lds[32768];
    ushortT* As = (ushortT*)lds;
    ushortT* Bs = (ushortT*)(lds + 8192);

    const int bm = blockIdx.x * 128;
    const int bn = blockIdx.y * 128;
    const int tid = threadIdx.x;
    const int w = tid >> 6, l = tid & 63;
    const int wm = w >> 1, wn = w & 1;

    f32x4 acc[4][4] = {};

    for (int kk = 0; kk < CC; kk += 32) {
        #pragma unroll
        for (int e = 0; e < 2; ++e) {
            const int D = (w * 2 + e) * 1024 + l * 16;
            const int r = D >> 6;
            const int c = (D & 63) >> 1;
            GLOAD_LDS16(A + (size_t)(bm + r) * CC + kk + c, lds + (w * 2 + e) * 1024);
            GLOAD_LDS16(B + (size_t)(bn + r) * CC + kk + c, lds + 8192 + (w * 2 + e) * 1024);
        }
        __syncthreads();
        short8 af[4], bfr[4];
        #pragma unroll
        for (int i = 0; i < 4; ++i) {
            int row = wm * 64 + i * 16 + (l & 15);
            af[i] = *(const short8*)(As + row * 32 + (l >> 4) * 8);
        }
        #pragma unroll
        for (int j = 0; j < 4; ++j) {
            int row = wn * 64 + j * 16 + (l & 15);
            bfr[j] = *(const short8*)(Bs + row * 32 + (l >> 4) * 8);
        }
        #pragma unroll
        for (int i = 0; i < 4; ++i)
            #pragma unroll
            for (int j = 0; j < 4; ++j)
                acc[i][j] = __builtin_amdgcn_mfma_f32_16x16x32_bf16(af[i], bfr[j], acc[i][j], 0, 0, 0);
        __syncthreads();
    }

    if (MODE == 1 || MODE == 3) {
        const float rsc = (MODE == 3) ? 0.18033688011112042f : 1.0f;  // 0.125*log2(e)
        float* cs = (float*)lds;
        float* sn = (float*)(lds + 16384);
        for (int idx = tid; idx < 128 * 32; idx += 256) {
            int rr = idx >> 5, cc2 = idx & 31;
            cs[idx] = fcos[(size_t)(bm + rr) * 32 + cc2];
            sn[idx] = fsin[(size_t)(bm + rr) * 32 + cc2];
        }
        __syncthreads();
        ushortT* dq = (ushortT*)dst;
        #pragma unroll
        for (int i = 0; i < 4; ++i)
            #pragma unroll
            for (int j = 0; j < 4; ++j)
                #pragma unroll
                for (int r = 0; r < 4; ++r) {
                    const int lt = wm * 64 + i * 16 + (l >> 4) * 4 + r;
                    const int o = bn + wn * 64 + j * 16 + (l & 15);
                    const float v = acc[i][j][r];
                    const float p = __shfl_xor(v, 1);
                    const int pp = (o & 63) >> 1;
                    const float cv = cs[lt * 32 + pp], sv = sn[lt * 32 + pp];
                    const float outv = ((o & 1) ? (p * sv + v * cv) : (v * cv - p * sv)) * rsc;
                    const int t = bm + lt, head = o >> 6, dd = o & 63;
                    dq[((size_t)head * TT + t) * HD + dd] = f2bf(outv);
                }
    } else if (MODE == 2) {
        ushortT* dv = (ushortT*)dst;
        #pragma unroll
        for (int i = 0; i < 4; ++i)
            #pragma unroll
            for (int j = 0; j < 4; ++j)
                #pragma unroll
                for (int r = 0; r < 4; ++r) {
                    const int t = bm + wm * 64 + i * 16 + (l >> 4) * 4 + r;
                    const int o = bn + wn * 64 + j * 16 + (l & 15);
                    const int head = o >> 6, dd = o & 63;
                    dv[((size_t)(head * HD + dd)) * TT + t] = f2bf(acc[i][j][r]);
                }
    } else {
        float* dout = (float*)dst;
        #pragma unroll
        for (int i = 0; i < 4; ++i)
            #pragma unroll
            for (int j = 0; j < 4; ++j)
                #pragma unroll
                for (int r = 0; r < 4; ++r) {
                    const int t = bm + wm * 64 + i * 16 + (l >> 4) * 4 + r;
                    const int o = bn + wn * 64 + j * 16 + (l & 15);
                    dout[(size_t)t * CC + o] = acc[i][j][r];
                }
    }
}

// ---------------------------------------------------------------------------
// bf16 MFMA flash attention, causal, split-KV for load balance.
// 88 chunks/head: cid<40 -> qb=cid, full range, direct y16 write;
// cid>=40 -> qb=40+(idx>>1), half-range chunk, f32 partial (y,m,l).
// Heavy chunks launch first (cid = 87 - blockIdx.x).
// ---------------------------------------------------------------------------
__global__ __launch_bounds__(256) void attn_mfma(
    const ushortT* __restrict__ q16, const ushortT* __restrict__ k16,
    const ushortT* __restrict__ vt16, ushortT* __restrict__ y16,
    char* __restrict__ parts)
{
    const int cid = 87 - (int)blockIdx.x;
    const int head = blockIdx.y;
    int qb, ci, kb0, kb1;
    if (cid < QB_SPLIT) { qb = cid; ci = -1; kb0 = 0; kb1 = qb; }
    else {
        const int idx = cid - QB_SPLIT;
        qb = QB_SPLIT + (idx >> 1);
        ci = idx & 1;
        const int mid = (qb + 1) >> 1;
        kb0 = ci ? mid : 0;
        kb1 = ci ? qb : mid - 1;
    }

    const int tid = threadIdx.x;
    const int w = tid >> 6, l = tid & 63;

    __shared__ char lds[40960];            // 2 x (K 8KB + Vt 8KB) + P 4x2KB
    char* Pbase = lds + 32768 + w * 2048;

    const int qrow = qb * 64 + w * 16 + (l & 15);
    short8 qa[2];
    {
        const ushortT* qp = q16 + ((size_t)head * TT + qrow) * HD + (l >> 4) * 8;
        qa[0] = *(const short8*)(qp);
        qa[1] = *(const short8*)(qp + 32);
    }

    f32x4 yacc[4] = {};
    float m_r[4], l_r[4];
    #pragma unroll
    for (int r = 0; r < 4; ++r) { m_r[r] = -1e30f; l_r[r] = 0.0f; }

    auto stage = [&](int kb, int base) {
        #pragma unroll
        for (int e = 0; e < 2; ++e) {
            const int D = (w * 2 + e) * 1024 + l * 16;
            const int row = D >> 7;
            const int src = D ^ ((row & 7) << 4);
            const int col = (src & 127) >> 1;
            GLOAD_LDS16(k16 + ((size_t)head * TT + (size_t)kb * 64 + row) * HD + col,
                        lds + base + (w * 2 + e) * 1024);
            GLOAD_LDS16(vt16 + ((size_t)head * HD + row) * TT + (size_t)kb * 64 + col,
                        lds + base + 8192 + (w * 2 + e) * 1024);
        }
    };

    int cur = 0;
    stage(kb0, 0);
    __syncthreads();

    for (int kb = kb0; kb <= kb1; ++kb) {
        if (kb + 1 <= kb1) stage(kb + 1, (cur ^ 1) * 16384);
        const char* Ks  = lds + cur * 16384;
        const char* Vts = Ks + 8192;

        f32x4 s[4] = {};
        #pragma unroll
        for (int ks = 0; ks < 2; ++ks)
            #pragma unroll
            for (int kg = 0; kg < 4; ++kg) {
                const int key = kg * 16 + (l & 15);
                int b = key * 128 + ks * 64 + (l >> 4) * 16;
                b ^= (key & 7) << 4;
                short8 kf = *(const short8*)(Ks + b);
                s[kg] = __builtin_amdgcn_mfma_f32_16x16x32_bf16(qa[ks], kf, s[kg], 0, 0, 0);
            }

        if (kb == qb) {   // diagonal tile only
            const int qg = qb * 64 + w * 16 + (l >> 4) * 4;
            #pragma unroll
            for (int kg = 0; kg < 4; ++kg)
                #pragma unroll
                for (int r = 0; r < 4; ++r)
                    if (kb * 64 + kg * 16 + (l & 15) > qg + r) s[kg][r] = -1e30f;
        }

        // tile max (cross-lane within 16-lane row groups)
        float mx[4];
        bool need = false;
        #pragma unroll
        for (int r = 0; r < 4; ++r) {
            float m0 = fmaxf(fmaxf(s[0][r], s[1][r]), fmaxf(s[2][r], s[3][r]));
            m0 = fmaxf(m0, __shfl_xor(m0, 1));
            m0 = fmaxf(m0, __shfl_xor(m0, 2));
            m0 = fmaxf(m0, __shfl_xor(m0, 4));
            m0 = fmaxf(m0, __shfl_xor(m0, 8));
            mx[r] = m0;
            need = need || (m0 - m_r[r] > 8.0f);
        }
        // defer-max: rescale only when some row grew by > 8 (exp2 domain)
        if (__any(need)) {
            #pragma unroll
            for (int r = 0; r < 4; ++r) {
                const float mnew = fmaxf(m_r[r], mx[r]);
                const float al = EXP2F(m_r[r] - mnew);
                m_r[r] = mnew;
                l_r[r] *= al;
                #pragma unroll
                for (int dg = 0; dg < 4; ++dg)
                    yacc[dg][r] *= al;
            }
        }
        // P = exp2(s - m), partial row sums (cross-lane reduce deferred)
        #pragma unroll
        for (int r = 0; r < 4; ++r) {
            float ls = 0.0f;
            #pragma unroll
            for (int kg = 0; kg < 4; ++kg) {
                float p = EXP2F(s[kg][r] - m_r[r]);
                s[kg][r] = p;
                ls += p;
            }
            l_r[r] += ls;
        }

        #pragma unroll
        for (int kg = 0; kg < 4; ++kg)
            #pragma unroll
            for (int r = 0; r < 4; ++r) {
                const int qq = (l >> 4) * 4 + r;
                int b = qq * 128 + (kg * 16 + (l & 15)) * 2;
                b ^= (qq & 7) << 4;
                *(ushortT*)(Pbase + b) = f2bf(s[kg][r]);
            }

        #pragma unroll
        for (int ks2 = 0; ks2 < 2; ++ks2) {
            const int qq = l & 15;
            int pb = qq * 128 + ks2 * 64 + (l >> 4) * 16;
            pb ^= (qq & 7) << 4;
            short8 pa = *(const short8*)(Pbase + pb);
            #pragma unroll
            for (int dg = 0; dg < 4; ++dg) {
                const int dd = dg * 16 + (l & 15);
                int vb = dd * 128 + ks2 * 64 + (l >> 4) * 16;
                vb ^= (dd & 7) << 4;
                short8 vf = *(const short8*)(Vts + vb);
                yacc[dg] = __builtin_amdgcn_mfma_f32_16x16x32_bf16(pa, vf, yacc[dg], 0, 0, 0);
            }
        }
        __syncthreads();
        cur ^= 1;
    }

    // reduce deferred row-sums across the 16-lane group
    float lsum[4];
    #pragma unroll
    for (int r = 0; r < 4; ++r) {
        float t = l_r[r];
        t += __shfl_xor(t, 1);
        t += __shfl_xor(t, 2);
        t += __shfl_xor(t, 4);
        t += __shfl_xor(t, 8);
        lsum[r] = t;
    }

    if (ci < 0) {
        #pragma unroll
        for (int r = 0; r < 4; ++r) lsum[r] = 1.0f / lsum[r];
        #pragma unroll
        for (int dg = 0; dg < 4; ++dg)
            #pragma unroll
            for (int r = 0; r < 4; ++r) {
                const int t = qb * 64 + w * 16 + (l >> 4) * 4 + r;
                const int c = head * HD + dg * 16 + (l & 15);
                y16[(size_t)t * CC + c] = f2bf(yacc[dg][r] * lsum[r]);
            }
    } else {
        char* pb = parts + (size_t)((head * 24 + (qb - QB_SPLIT)) * 2 + ci) * PSLOT_BYTES;
        float* yp = (float*)pb;
        float* mp = (float*)(pb + 16384);
        float* lp = mp + 64;
        #pragma unroll
        for (int dg = 0; dg < 4; ++dg)
            #pragma unroll
            for (int r = 0; r < 4; ++r) {
                const int row = w * 16 + (l >> 4) * 4 + r;
                const int col = dg * 16 + (l & 15);
                yp[row * 64 + col] = yacc[dg][r];
            }
        if ((l & 15) == 0) {
            #pragma unroll
            for (int r = 0; r < 4; ++r) {
                const int row = w * 16 + (l >> 4) * 4 + r;
                mp[row] = m_r[r];
                lp[row] = lsum[r];
            }
        }
    }
}

// ---------------------------------------------------------------------------
// Merge the two partial chunks for qb in [QB_SPLIT, 64).
// ---------------------------------------------------------------------------
__global__ __launch_bounds__(256) void attn_combine(
    const char* __restrict__ parts, ushortT* __restrict__ y16)
{
    const int qb = QB_SPLIT + blockIdx.x;
    const int head = blockIdx.y;
    const int tid = threadIdx.x;
    const int row = tid >> 2;
    const int pc = tid & 3;

    const char* p0 = parts + (size_t)((head * 24 + (qb - QB_SPLIT)) * 2) * PSLOT_BYTES;
    const char* p1 = p0 + PSLOT_BYTES;
    const float* y0 = (const float*)p0;
    const float* y1 = (const float*)p1;
    const float* m0p = (const float*)(p0 + 16384);
    const float* m1p = (const float*)(p1 + 16384);
    const float m0 = m0p[row], m1 = m1p[row];
    const float l0 = m0p[64 + row], l1 = m1p[64 + row];
    const float M = fmaxf(m0, m1);
    const float w0 = EXP2F(m0 - M), w1 = EXP2F(m1 - M);
    const float Linv = 1.0f / (l0 * w0 + l1 * w1);

    const int t = qb * 64 + row;
    #pragma unroll
    for (int j = 0; j < 16; ++j) {
        const int c = pc * 16 + j;
        const float v = (y0[row * 64 + c] * w0 + y1[row * 64 + c] * w1) * Linv;
        y16[(size_t)t * CC + head * HD + c] = f2bf(v);
    }
}

extern "C" void kernel_launch(void* const* d_in, const int* in_sizes, int n_in,
                              void* d_out, int out_size, void* d_ws, size_t ws_size,
                              hipStream_t stream) {
    const float* x    = (const float*)d_in[0];
    const float* fcos = (const float*)d_in[1];
    const float* fsin = (const float*)d_in[2];
    const float* Wq   = (const float*)d_in[3];
    const float* Wk   = (const float*)d_in[4];
    const float* Wv   = (const float*)d_in[5];
    const float* Wo   = (const float*)d_in[6];
    float* out = (float*)d_out;

    char* ws = (char*)d_ws;
    ushortT* xb  = (ushortT*)(ws);                 // [0,8MB)  dead after QKV GEMMs
    ushortT* wqb = (ushortT*)(ws + (8u << 20));    // [8,10MB) dead after Q GEMM
    ushortT* wkb = (ushortT*)(ws + (10u << 20));
    ushortT* wvb = (ushortT*)(ws + (12u << 20));
    ushortT* wob = (ushortT*)(ws + (14u << 20));   // LIVE until final GEMM
    ushortT* q16 = (ushortT*)(ws + (16u << 20));
    ushortT* k16 = (ushortT*)(ws + (24u << 20));
    ushortT* vt16 = (ushortT*)(ws + (32u << 20));
    ushortT* y16 = (ushortT*)(ws + (40u << 20));
    char* parts = ws;   // [0, 12.98MB) — only overlaps dead xb/wqb/wkb regions

    const int nx = TT * CC, nw = CC * CC;
    cvt_bf16<<<nx / 4 / 256, 256, 0, stream>>>(x, xb, nx);
    cvt_bf16<<<nw / 4 / 256, 256, 0, stream>>>(Wq, wqb, nw);
    cvt_bf16<<<nw / 4 / 256, 256, 0, stream>>>(Wk, wkb, nw);
    cvt_bf16<<<nw / 4 / 256, 256, 0, stream>>>(Wv, wvb, nw);
    cvt_bf16<<<nw / 4 / 256, 256, 0, stream>>>(Wo, wob, nw);

    dim3 ggrid(TT / 128, CC / 128);
    gemm_mfma<3><<<ggrid, 256, 0, stream>>>(xb, wqb, fcos, fsin, q16);
    gemm_mfma<1><<<ggrid, 256, 0, stream>>>(xb, wkb, fcos, fsin, k16);
    gemm_mfma<2><<<ggrid, 256, 0, stream>>>(xb, wvb, fcos, fsin, vt16);

    dim3 agrid(88, NH);
    attn_mfma<<<agrid, 256, 0, stream>>>(q16, k16, vt16, y16, parts);

    dim3 cgrid(64 - QB_SPLIT, NH);
    attn_combine<<<cgrid, 256, 0, stream>>>(parts, y16);

    gemm_mfma<0><<<ggrid, 256, 0, stream>>>(y16, wob, fcos, fsin, out);
}

// Round 7
// 216.215 us; speedup vs baseline: 10.5394x; 1.1164x over previous
//
#include <hip/hip_runtime.h>
#include <hip/hip_bf16.h>
#include <math.h>

#define TT 4096
#define CC 1024
#define NH 16
#define HD 64

typedef unsigned short ushortT;
typedef __attribute__((ext_vector_type(8))) short short8;
typedef __attribute__((ext_vector_type(4))) float f32x4;

#define GLOAD_LDS16(gp, lp)                                                   \
    __builtin_amdgcn_global_load_lds(                                         \
        (const __attribute__((address_space(1))) void*)(gp),                  \
        (__attribute__((address_space(3))) void*)(lp), 16, 0, 0)

#define EXP2F(x) __builtin_amdgcn_exp2f(x)   // single v_exp_f32

__device__ __forceinline__ ushortT f2bf(float f) {
    __hip_bfloat16 h = __float2bfloat16(f);
    ushortT u; __builtin_memcpy(&u, &h, 2); return u;
}

// Partial-attention slot (f32): y[64][64] + m[64] + l[64] = 16384+256+256
#define PSLOT_BYTES 16896
#define QB_SPLIT 40   // qb >= QB_SPLIT uses 2 chunks; 16*24*2*16896 = 12.98MB < 14MB

// ---------------------------------------------------------------------------
__global__ __launch_bounds__(256) void cvt_bf16(const float* __restrict__ src,
                                                ushortT* __restrict__ dst, int n) {
    int i = (blockIdx.x * 256 + threadIdx.x) * 4;
    if (i < n) {
        float4 v = *(const float4*)(src + i);
        *(ushort4*)(dst + i) = make_ushort4(f2bf(v.x), f2bf(v.y), f2bf(v.z), f2bf(v.w));
    }
}

// ---------------------------------------------------------------------------
// bf16 MFMA GEMM: C[t,o] = sum_c A[t,c]*B[o,c].  128x128 tile, BK=32, 4 waves.
// XCD-aware tile swizzle (grid 32x8 = 256 wgs, 256%8==0 -> bijective).
// MODE 0: fp32 out [T][C]
// MODE 1: RoPE -> bf16 [h][T][d]                          (K)
// MODE 3: RoPE scaled by 0.125*log2(e) -> bf16 [h][T][d]  (Q)
// MODE 2: bf16 V^T [h][d][T]
// ---------------------------------------------------------------------------
template <int MODE>
__global__ __launch_bounds__(256) void gemm_mfma(
    const ushortT* __restrict__ A, const ushortT* __restrict__ B,
    const float* __restrict__ fcos, const float* __restrict__ fsin,
    void* __restrict__ dst)
{
    __shared__ char lds[32768];
    ushortT* As = (ushortT*)lds;
    ushortT* Bs = (ushortT*)(lds + 8192);

    const int lin = (int)(blockIdx.y * gridDim.x + blockIdx.x);
    const int nwg8 = (int)((gridDim.x * gridDim.y) >> 3);
    const int swz = (lin & 7) * nwg8 + (lin >> 3);
    const int bm = (swz % (int)gridDim.x) * 128;
    const int bn = (swz / (int)gridDim.x) * 128;
    const int tid = threadIdx.x;
    const int w = tid >> 6, l = tid & 63;
    const int wm = w >> 1, wn = w & 1;

    f32x4 acc[4][4] = {};

    for (int kk = 0; kk < CC; kk += 32) {
        #pragma unroll
        for (int e = 0; e < 2; ++e) {
            const int D = (w * 2 + e) * 1024 + l * 16;
            const int r = D >> 6;
            const int c = (D & 63) >> 1;
            GLOAD_LDS16(A + (size_t)(bm + r) * CC + kk + c, lds + (w * 2 + e) * 1024);
            GLOAD_LDS16(B + (size_t)(bn + r) * CC + kk + c, lds + 8192 + (w * 2 + e) * 1024);
        }
        __syncthreads();
        short8 af[4], bfr[4];
        #pragma unroll
        for (int i = 0; i < 4; ++i) {
            int row = wm * 64 + i * 16 + (l & 15);
            af[i] = *(const short8*)(As + row * 32 + (l >> 4) * 8);
        }
        #pragma unroll
        for (int j = 0; j < 4; ++j) {
            int row = wn * 64 + j * 16 + (l & 15);
            bfr[j] = *(const short8*)(Bs + row * 32 + (l >> 4) * 8);
        }
        #pragma unroll
        for (int i = 0; i < 4; ++i)
            #pragma unroll
            for (int j = 0; j < 4; ++j)
                acc[i][j] = __builtin_amdgcn_mfma_f32_16x16x32_bf16(af[i], bfr[j], acc[i][j], 0, 0, 0);
        __syncthreads();
    }

    if (MODE == 1 || MODE == 3) {
        const float rsc = (MODE == 3) ? 0.18033688011112042f : 1.0f;  // 0.125*log2(e)
        float* cs = (float*)lds;
        float* sn = (float*)(lds + 16384);
        for (int idx = tid; idx < 128 * 32; idx += 256) {
            int rr = idx >> 5, cc2 = idx & 31;
            cs[idx] = fcos[(size_t)(bm + rr) * 32 + cc2];
            sn[idx] = fsin[(size_t)(bm + rr) * 32 + cc2];
        }
        __syncthreads();
        ushortT* dq = (ushortT*)dst;
        #pragma unroll
        for (int i = 0; i < 4; ++i)
            #pragma unroll
            for (int j = 0; j < 4; ++j)
                #pragma unroll
                for (int r = 0; r < 4; ++r) {
                    const int lt = wm * 64 + i * 16 + (l >> 4) * 4 + r;
                    const int o = bn + wn * 64 + j * 16 + (l & 15);
                    const float v = acc[i][j][r];
                    const float p = __shfl_xor(v, 1);
                    const int pp = (o & 63) >> 1;
                    const float cv = cs[lt * 32 + pp], sv = sn[lt * 32 + pp];
                    const float outv = ((o & 1) ? (p * sv + v * cv) : (v * cv - p * sv)) * rsc;
                    const int t = bm + lt, head = o >> 6, dd = o & 63;
                    dq[((size_t)head * TT + t) * HD + dd] = f2bf(outv);
                }
    } else if (MODE == 2) {
        ushortT* dv = (ushortT*)dst;
        #pragma unroll
        for (int i = 0; i < 4; ++i)
            #pragma unroll
            for (int j = 0; j < 4; ++j)
                #pragma unroll
                for (int r = 0; r < 4; ++r) {
                    const int t = bm + wm * 64 + i * 16 + (l >> 4) * 4 + r;
                    const int o = bn + wn * 64 + j * 16 + (l & 15);
                    const int head = o >> 6, dd = o & 63;
                    dv[((size_t)(head * HD + dd)) * TT + t] = f2bf(acc[i][j][r]);
                }
    } else {
        float* dout = (float*)dst;
        #pragma unroll
        for (int i = 0; i < 4; ++i)
            #pragma unroll
            for (int j = 0; j < 4; ++j)
                #pragma unroll
                for (int r = 0; r < 4; ++r) {
                    const int t = bm + wm * 64 + i * 16 + (l >> 4) * 4 + r;
                    const int o = bn + wn * 64 + j * 16 + (l & 15);
                    dout[(size_t)t * CC + o] = acc[i][j][r];
                }
    }
}

// ---------------------------------------------------------------------------
// bf16 MFMA flash attention, causal, split-KV, counted-vmcnt 2-phase pipeline.
// 88 chunks/head: cid<40 -> qb=cid, full range, direct y16 write;
// cid>=40 -> qb=40+(idx>>1), half-range chunk, f32 partial (y,m,l).
// Heavy chunks launch first (cid = 87 - blockIdx.x).
// ---------------------------------------------------------------------------
__global__ __launch_bounds__(256) void attn_mfma(
    const ushortT* __restrict__ q16, const ushortT* __restrict__ k16,
    const ushortT* __restrict__ vt16, ushortT* __restrict__ y16,
    char* __restrict__ parts)
{
    const int cid = 87 - (int)blockIdx.x;
    const int head = blockIdx.y;
    int qb, ci, kb0, kb1;
    if (cid < QB_SPLIT) { qb = cid; ci = -1; kb0 = 0; kb1 = qb; }
    else {
        const int idx = cid - QB_SPLIT;
        qb = QB_SPLIT + (idx >> 1);
        ci = idx & 1;
        const int mid = (qb + 1) >> 1;
        kb0 = ci ? mid : 0;
        kb1 = ci ? qb : mid - 1;
    }

    const int tid = threadIdx.x;
    const int w = tid >> 6, l = tid & 63;

    __shared__ char lds[40960];            // 2 x (K 8KB + Vt 8KB) + P 4x2KB
    char* Pbase = lds + 32768 + w * 2048;

    const int qrow = qb * 64 + w * 16 + (l & 15);
    short8 qa[2];
    {
        const ushortT* qp = q16 + ((size_t)head * TT + qrow) * HD + (l >> 4) * 8;
        qa[0] = *(const short8*)(qp);
        qa[1] = *(const short8*)(qp + 32);
    }

    f32x4 yacc[4] = {};
    float m_r[4], l_r[4];
    #pragma unroll
    for (int r = 0; r < 4; ++r) { m_r[r] = -1e30f; l_r[r] = 0.0f; }

    auto stage = [&](int kb, int base) {
        #pragma unroll
        for (int e = 0; e < 2; ++e) {
            const int D = (w * 2 + e) * 1024 + l * 16;
            const int row = D >> 7;
            const int src = D ^ ((row & 7) << 4);
            const int col = (src & 127) >> 1;
            GLOAD_LDS16(k16 + ((size_t)head * TT + (size_t)kb * 64 + row) * HD + col,
                        lds + base + (w * 2 + e) * 1024);
            GLOAD_LDS16(vt16 + ((size_t)head * HD + row) * TT + (size_t)kb * 64 + col,
                        lds + base + 8192 + (w * 2 + e) * 1024);
        }
    };

    int cur = 0;
    stage(kb0, 0);

    for (int kb = kb0; kb <= kb1; ++kb) {
        // Prefetch next tile, then wait only for the CURRENT tile's 4 loads
        // (counted vmcnt keeps the prefetch in flight across both barriers).
        if (kb + 1 <= kb1) {
            stage(kb + 1, (cur ^ 1) * 16384);
            asm volatile("s_waitcnt vmcnt(4)" ::: "memory");
        } else {
            asm volatile("s_waitcnt vmcnt(0)" ::: "memory");
        }
        __builtin_amdgcn_s_barrier();          // current buffer ready for all waves
        __builtin_amdgcn_sched_barrier(0);

        const char* Ks  = lds + cur * 16384;
        const char* Vts = Ks + 8192;

        f32x4 s[4] = {};
        #pragma unroll
        for (int ks = 0; ks < 2; ++ks)
            #pragma unroll
            for (int kg = 0; kg < 4; ++kg) {
                const int key = kg * 16 + (l & 15);
                int b = key * 128 + ks * 64 + (l >> 4) * 16;
                b ^= (key & 7) << 4;
                short8 kf = *(const short8*)(Ks + b);
                s[kg] = __builtin_amdgcn_mfma_f32_16x16x32_bf16(qa[ks], kf, s[kg], 0, 0, 0);
            }

        if (kb == qb) {   // diagonal tile only
            const int qg = qb * 64 + w * 16 + (l >> 4) * 4;
            #pragma unroll
            for (int kg = 0; kg < 4; ++kg)
                #pragma unroll
                for (int r = 0; r < 4; ++r)
                    if (kb * 64 + kg * 16 + (l & 15) > qg + r) s[kg][r] = -1e30f;
        }

        // in-lane defer-max check: no cross-lane traffic in steady state
        float ilmax[4];
        bool need = false;
        #pragma unroll
        for (int r = 0; r < 4; ++r) {
            const float m0 = fmaxf(fmaxf(s[0][r], s[1][r]), fmaxf(s[2][r], s[3][r]));
            ilmax[r] = m0;
            need = need || (m0 > m_r[r] + 8.0f);
        }
        if (__any(need)) {
            #pragma unroll
            for (int r = 0; r < 4; ++r) {
                float m0 = ilmax[r];
                m0 = fmaxf(m0, __shfl_xor(m0, 1));
                m0 = fmaxf(m0, __shfl_xor(m0, 2));
                m0 = fmaxf(m0, __shfl_xor(m0, 4));
                m0 = fmaxf(m0, __shfl_xor(m0, 8));
                const float mnew = fmaxf(m_r[r], m0);
                const float al = EXP2F(m_r[r] - mnew);
                m_r[r] = mnew;
                l_r[r] *= al;
                #pragma unroll
                for (int dg = 0; dg < 4; ++dg)
                    yacc[dg][r] *= al;
            }
        }
        // P = exp2(s - m), partial row sums (cross-lane reduce deferred)
        #pragma unroll
        for (int r = 0; r < 4; ++r) {
            float ls = 0.0f;
            #pragma unroll
            for (int kg = 0; kg < 4; ++kg) {
                float p = EXP2F(s[kg][r] - m_r[r]);
                s[kg][r] = p;
                ls += p;
            }
            l_r[r] += ls;
        }

        #pragma unroll
        for (int kg = 0; kg < 4; ++kg)
            #pragma unroll
            for (int r = 0; r < 4; ++r) {
                const int qq = (l >> 4) * 4 + r;
                int b = qq * 128 + (kg * 16 + (l & 15)) * 2;
                b ^= (qq & 7) << 4;
                *(ushortT*)(Pbase + b) = f2bf(s[kg][r]);
            }

        #pragma unroll
        for (int ks2 = 0; ks2 < 2; ++ks2) {
            const int qq = l & 15;
            int pb = qq * 128 + ks2 * 64 + (l >> 4) * 16;
            pb ^= (qq & 7) << 4;
            short8 pa = *(const short8*)(Pbase + pb);
            #pragma unroll
            for (int dg = 0; dg < 4; ++dg) {
                const int dd = dg * 16 + (l & 15);
                int vb = dd * 128 + ks2 * 64 + (l >> 4) * 16;
                vb ^= (dd & 7) << 4;
                short8 vf = *(const short8*)(Vts + vb);
                yacc[dg] = __builtin_amdgcn_mfma_f32_16x16x32_bf16(pa, vf, yacc[dg], 0, 0, 0);
            }
        }
        __builtin_amdgcn_s_barrier();          // all waves done reading cur
        cur ^= 1;
    }

    // reduce deferred row-sums across the 16-lane group
    float lsum[4];
    #pragma unroll
    for (int r = 0; r < 4; ++r) {
        float t = l_r[r];
        t += __shfl_xor(t, 1);
        t += __shfl_xor(t, 2);
        t += __shfl_xor(t, 4);
        t += __shfl_xor(t, 8);
        lsum[r] = t;
    }

    if (ci < 0) {
        #pragma unroll
        for (int r = 0; r < 4; ++r) lsum[r] = 1.0f / lsum[r];
        #pragma unroll
        for (int dg = 0; dg < 4; ++dg)
            #pragma unroll
            for (int r = 0; r < 4; ++r) {
                const int t = qb * 64 + w * 16 + (l >> 4) * 4 + r;
                const int c = head * HD + dg * 16 + (l & 15);
                y16[(size_t)t * CC + c] = f2bf(yacc[dg][r] * lsum[r]);
            }
    } else {
        char* pb = parts + (size_t)((head * 24 + (qb - QB_SPLIT)) * 2 + ci) * PSLOT_BYTES;
        float* yp = (float*)pb;
        float* mp = (float*)(pb + 16384);
        float* lp = mp + 64;
        #pragma unroll
        for (int dg = 0; dg < 4; ++dg)
            #pragma unroll
            for (int r = 0; r < 4; ++r) {
                const int row = w * 16 + (l >> 4) * 4 + r;
                const int col = dg * 16 + (l & 15);
                yp[row * 64 + col] = yacc[dg][r];
            }
        if ((l & 15) == 0) {
            #pragma unroll
            for (int r = 0; r < 4; ++r) {
                const int row = w * 16 + (l >> 4) * 4 + r;
                mp[row] = m_r[r];
                lp[row] = lsum[r];
            }
        }
    }
}

// ---------------------------------------------------------------------------
// Merge the two partial chunks for qb in [QB_SPLIT, 64).
// ---------------------------------------------------------------------------
__global__ __launch_bounds__(256) void attn_combine(
    const char* __restrict__ parts, ushortT* __restrict__ y16)
{
    const int qb = QB_SPLIT + blockIdx.x;
    const int head = blockIdx.y;
    const int tid = threadIdx.x;
    const int row = tid >> 2;
    const int pc = tid & 3;

    const char* p0 = parts + (size_t)((head * 24 + (qb - QB_SPLIT)) * 2) * PSLOT_BYTES;
    const char* p1 = p0 + PSLOT_BYTES;
    const float* y0 = (const float*)p0;
    const float* y1 = (const float*)p1;
    const float* m0p = (const float*)(p0 + 16384);
    const float* m1p = (const float*)(p1 + 16384);
    const float m0 = m0p[row], m1 = m1p[row];
    const float l0 = m0p[64 + row], l1 = m1p[64 + row];
    const float M = fmaxf(m0, m1);
    const float w0 = EXP2F(m0 - M), w1 = EXP2F(m1 - M);
    const float Linv = 1.0f / (l0 * w0 + l1 * w1);

    const int t = qb * 64 + row;
    #pragma unroll
    for (int j = 0; j < 16; ++j) {
        const int c = pc * 16 + j;
        const float v = (y0[row * 64 + c] * w0 + y1[row * 64 + c] * w1) * Linv;
        y16[(size_t)t * CC + head * HD + c] = f2bf(v);
    }
}

extern "C" void kernel_launch(void* const* d_in, const int* in_sizes, int n_in,
                              void* d_out, int out_size, void* d_ws, size_t ws_size,
                              hipStream_t stream) {
    const float* x    = (const float*)d_in[0];
    const float* fcos = (const float*)d_in[1];
    const float* fsin = (const float*)d_in[2];
    const float* Wq   = (const float*)d_in[3];
    const float* Wk   = (const float*)d_in[4];
    const float* Wv   = (const float*)d_in[5];
    const float* Wo   = (const float*)d_in[6];
    float* out = (float*)d_out;

    char* ws = (char*)d_ws;
    ushortT* xb  = (ushortT*)(ws);                 // [0,8MB)  dead after QKV GEMMs
    ushortT* wqb = (ushortT*)(ws + (8u << 20));    // [8,10MB) dead after Q GEMM
    ushortT* wkb = (ushortT*)(ws + (10u << 20));
    ushortT* wvb = (ushortT*)(ws + (12u << 20));
    ushortT* wob = (ushortT*)(ws + (14u << 20));   // LIVE until final GEMM
    ushortT* q16 = (ushortT*)(ws + (16u << 20));
    ushortT* k16 = (ushortT*)(ws + (24u << 20));
    ushortT* vt16 = (ushortT*)(ws + (32u << 20));
    ushortT* y16 = (ushortT*)(ws + (40u << 20));
    char* parts = ws;   // [0, 12.98MB) — only overlaps dead xb/wqb/wkb regions

    const int nx = TT * CC, nw = CC * CC;
    cvt_bf16<<<nx / 4 / 256, 256, 0, stream>>>(x, xb, nx);
    cvt_bf16<<<nw / 4 / 256, 256, 0, stream>>>(Wq, wqb, nw);
    cvt_bf16<<<nw / 4 / 256, 256, 0, stream>>>(Wk, wkb, nw);
    cvt_bf16<<<nw / 4 / 256, 256, 0, stream>>>(Wv, wvb, nw);
    cvt_bf16<<<nw / 4 / 256, 256, 0, stream>>>(Wo, wob, nw);

    dim3 ggrid(TT / 128, CC / 128);
    gemm_mfma<3><<<ggrid, 256, 0, stream>>>(xb, wqb, fcos, fsin, q16);
    gemm_mfma<1><<<ggrid, 256, 0, stream>>>(xb, wkb, fcos, fsin, k16);
    gemm_mfma<2><<<ggrid, 256, 0, stream>>>(xb, wvb, fcos, fsin, vt16);

    dim3 agrid(88, NH);
    attn_mfma<<<agrid, 256, 0, stream>>>(q16, k16, vt16, y16, parts);

    dim3 cgrid(64 - QB_SPLIT, NH);
    attn_combine<<<cgrid, 256, 0, stream>>>(parts, y16);

    gemm_mfma<0><<<ggrid, 256, 0, stream>>>(y16, wob, fcos, fsin, out);
}

// Round 8
// 181.446 us; speedup vs baseline: 12.5590x; 1.1916x over previous
//
#include <hip/hip_runtime.h>
#include <hip/hip_bf16.h>
#include <math.h>

#define TT 4096
#define CC 1024
#define NH 16
#define HD 64

typedef unsigned short ushortT;
typedef __attribute__((ext_vector_type(8))) short short8;
typedef __attribute__((ext_vector_type(4))) float f32x4;

#define GLOAD_LDS16(gp, lp)                                                   \
    __builtin_amdgcn_global_load_lds(                                         \
        (const __attribute__((address_space(1))) void*)(gp),                  \
        (__attribute__((address_space(3))) void*)(lp), 16, 0, 0)

#define EXP2F(x) __builtin_amdgcn_exp2f(x)   // single v_exp_f32

__device__ __forceinline__ ushortT f2bf(float f) {
    __hip_bfloat16 h = __float2bfloat16(f);
    ushortT u; __builtin_memcpy(&u, &h, 2); return u;
}

// Partial-attention slot (f32): y[64][64] + m[64] + l[64] = 16384+256+256
#define PSLOT_BYTES 16896
#define QB_SPLIT 40   // qb >= QB_SPLIT uses 2 chunks; 16*24*2*16896 = 12.38MB < 13MB
#define NCHUNK 88

// ---------------------------------------------------------------------------
// One fused f32->bf16 conversion over x and the four weights.
// ---------------------------------------------------------------------------
__global__ __launch_bounds__(256) void cvt_all(
    const float* __restrict__ x,  const float* __restrict__ wq,
    const float* __restrict__ wk, const float* __restrict__ wv,
    const float* __restrict__ wo,
    ushortT* __restrict__ xb,  ushortT* __restrict__ wqb,
    ushortT* __restrict__ wkb, ushortT* __restrict__ wvb,
    ushortT* __restrict__ wob)
{
    const int i = (blockIdx.x * 256 + threadIdx.x) * 4;
    const int NX = TT * CC, NW = CC * CC;
    const float* s; ushortT* d; int off;
    if (i < NX)               { s = x;  d = xb;  off = i; }
    else if (i < NX + NW)     { s = wq; d = wqb; off = i - NX; }
    else if (i < NX + 2 * NW) { s = wk; d = wkb; off = i - NX - NW; }
    else if (i < NX + 3 * NW) { s = wv; d = wvb; off = i - NX - 2 * NW; }
    else                      { s = wo; d = wob; off = i - NX - 3 * NW; }
    float4 v = *(const float4*)(s + off);
    *(ushort4*)(d + off) = make_ushort4(f2bf(v.x), f2bf(v.y), f2bf(v.z), f2bf(v.w));
}

// ---------------------------------------------------------------------------
// bf16 MFMA GEMM: C[t,o] = sum_c A[t,c]*B[o,c].  128x128 tile, BK=32, 4 waves.
// 3-buffer depth-2 counted-vmcnt pipeline (no barrier drain in main loop).
// XCD-aware tile swizzle (grid 32x8 = 256 wgs, 256%8==0 -> bijective).
// MODE 0: fp32 out [T][C]
// MODE 1: RoPE -> bf16 [h][T][d]                          (K)
// MODE 3: RoPE scaled by 0.125*log2(e) -> bf16 [h][T][d]  (Q)
// MODE 2: bf16 V^T [h][d][T]
// ---------------------------------------------------------------------------
template <int MODE>
__global__ __launch_bounds__(256) void gemm_mfma(
    const ushortT* __restrict__ A, const ushortT* __restrict__ B,
    const float* __restrict__ fcos, const float* __restrict__ fsin,
    void* __restrict__ dst)
{
    __shared__ char lds[49152];            // 3 x (A 8KB + B 8KB)

    const int lin = (int)(blockIdx.y * gridDim.x + blockIdx.x);
    const int nwg8 = (int)((gridDim.x * gridDim.y) >> 3);
    const int swz = (lin & 7) * nwg8 + (lin >> 3);
    const int bm = (swz % (int)gridDim.x) * 128;
    const int bn = (swz / (int)gridDim.x) * 128;
    const int tid = threadIdx.x;
    const int w = tid >> 6, l = tid & 63;
    const int wm = w >> 1, wn = w & 1;

    f32x4 acc[4][4] = {};

    auto stageg = [&](int kk, int base) {
        #pragma unroll
        for (int e = 0; e < 2; ++e) {
            const int D = (w * 2 + e) * 1024 + l * 16;
            const int r = D >> 6;
            const int c = (D & 63) >> 1;
            GLOAD_LDS16(A + (size_t)(bm + r) * CC + kk + c, lds + base + (w * 2 + e) * 1024);
            GLOAD_LDS16(B + (size_t)(bn + r) * CC + kk + c, lds + base + 8192 + (w * 2 + e) * 1024);
        }
    };

    stageg(0, 0);
    stageg(32, 16384);

    for (int kt = 0; kt < 32; ++kt) {
        const int cur = kt % 3;
        if (kt + 2 < 32) {
            stageg((kt + 2) * 32, ((kt + 2) % 3) * 16384);
            asm volatile("s_waitcnt vmcnt(8)" ::: "memory");
        } else if (kt + 1 < 32) {
            asm volatile("s_waitcnt vmcnt(4)" ::: "memory");
        } else {
            asm volatile("s_waitcnt vmcnt(0)" ::: "memory");
        }
        __builtin_amdgcn_s_barrier();
        __builtin_amdgcn_sched_barrier(0);

        const ushortT* As = (const ushortT*)(lds + cur * 16384);
        const ushortT* Bs = (const ushortT*)(lds + cur * 16384 + 8192);

        short8 af[4], bfr[4];
        #pragma unroll
        for (int i = 0; i < 4; ++i) {
            int row = wm * 64 + i * 16 + (l & 15);
            af[i] = *(const short8*)(As + row * 32 + (l >> 4) * 8);
        }
        #pragma unroll
        for (int j = 0; j < 4; ++j) {
            int row = wn * 64 + j * 16 + (l & 15);
            bfr[j] = *(const short8*)(Bs + row * 32 + (l >> 4) * 8);
        }
        #pragma unroll
        for (int i = 0; i < 4; ++i)
            #pragma unroll
            for (int j = 0; j < 4; ++j)
                acc[i][j] = __builtin_amdgcn_mfma_f32_16x16x32_bf16(af[i], bfr[j], acc[i][j], 0, 0, 0);
        __builtin_amdgcn_s_barrier();
    }

    if (MODE == 1 || MODE == 3) {
        const float rsc = (MODE == 3) ? 0.18033688011112042f : 1.0f;  // 0.125*log2(e)
        float* cs = (float*)lds;
        float* sn = (float*)(lds + 16384);
        for (int idx = tid; idx < 128 * 32; idx += 256) {
            int rr = idx >> 5, cc2 = idx & 31;
            cs[idx] = fcos[(size_t)(bm + rr) * 32 + cc2];
            sn[idx] = fsin[(size_t)(bm + rr) * 32 + cc2];
        }
        __syncthreads();
        ushortT* dq = (ushortT*)dst;
        #pragma unroll
        for (int i = 0; i < 4; ++i)
            #pragma unroll
            for (int j = 0; j < 4; ++j)
                #pragma unroll
                for (int r = 0; r < 4; ++r) {
                    const int lt = wm * 64 + i * 16 + (l >> 4) * 4 + r;
                    const int o = bn + wn * 64 + j * 16 + (l & 15);
                    const float v = acc[i][j][r];
                    const float p = __shfl_xor(v, 1);
                    const int pp = (o & 63) >> 1;
                    const float cv = cs[lt * 32 + pp], sv = sn[lt * 32 + pp];
                    const float outv = ((o & 1) ? (p * sv + v * cv) : (v * cv - p * sv)) * rsc;
                    const int t = bm + lt, head = o >> 6, dd = o & 63;
                    dq[((size_t)head * TT + t) * HD + dd] = f2bf(outv);
                }
    } else if (MODE == 2) {
        ushortT* dv = (ushortT*)dst;
        #pragma unroll
        for (int i = 0; i < 4; ++i)
            #pragma unroll
            for (int j = 0; j < 4; ++j)
                #pragma unroll
                for (int r = 0; r < 4; ++r) {
                    const int t = bm + wm * 64 + i * 16 + (l >> 4) * 4 + r;
                    const int o = bn + wn * 64 + j * 16 + (l & 15);
                    const int head = o >> 6, dd = o & 63;
                    dv[((size_t)(head * HD + dd)) * TT + t] = f2bf(acc[i][j][r]);
                }
    } else {
        float* dout = (float*)dst;
        #pragma unroll
        for (int i = 0; i < 4; ++i)
            #pragma unroll
            for (int j = 0; j < 4; ++j)
                #pragma unroll
                for (int r = 0; r < 4; ++r) {
                    const int t = bm + wm * 64 + i * 16 + (l >> 4) * 4 + r;
                    const int o = bn + wn * 64 + j * 16 + (l & 15);
                    dout[(size_t)t * CC + o] = acc[i][j][r];
                }
    }
}

// ---------------------------------------------------------------------------
// bf16 MFMA flash attention, causal, split-KV, counted-vmcnt 2-phase pipeline,
// persistent blocks + work-stealing over (head, chunk) tickets.
// 88 chunks/head: cid<40 -> qb=cid, full range, direct y16 write;
// cid>=40 -> qb=40+(idx>>1), half-range chunk, f32 partial (y,m,l).
// Ticket order: o=tk>>4 -> cid=87-o (splits first, then heavy fulls).
// ---------------------------------------------------------------------------
__global__ __launch_bounds__(256) void attn_mfma(
    const ushortT* __restrict__ q16, const ushortT* __restrict__ k16,
    const ushortT* __restrict__ vt16, ushortT* __restrict__ y16,
    char* __restrict__ parts, int* __restrict__ counter)
{
    const int tid = threadIdx.x;
    const int w = tid >> 6, l = tid & 63;

    __shared__ char lds[40960];            // 2 x (K 8KB + Vt 8KB) + P 4x2KB
    char* Pbase = lds + 32768 + w * 2048;

    for (;;) {
        // ---- pull a ticket (broadcast through dead K-buffer word) ----
        if (tid == 0) {
            int tk0 = atomicAdd(counter, 1);
            *(int*)lds = tk0;
        }
        __syncthreads();
        const int tk = *(const int*)lds;
        __syncthreads();                   // all read before staging overwrites
        if (tk >= NCHUNK * NH) break;

        const int head = tk & 15;
        const int cid = 87 - (tk >> 4);
        int qb, ci, kb0, kb1;
        if (cid < QB_SPLIT) { qb = cid; ci = -1; kb0 = 0; kb1 = qb; }
        else {
            const int idx = cid - QB_SPLIT;
            qb = QB_SPLIT + (idx >> 1);
            ci = idx & 1;
            const int mid = (qb + 1) >> 1;
            kb0 = ci ? mid : 0;
            kb1 = ci ? qb : mid - 1;
        }

        const int qrow = qb * 64 + w * 16 + (l & 15);
        short8 qa[2];
        {
            const ushortT* qp = q16 + ((size_t)head * TT + qrow) * HD + (l >> 4) * 8;
            qa[0] = *(const short8*)(qp);
            qa[1] = *(const short8*)(qp + 32);
        }

        f32x4 yacc[4] = {};
        float m_r[4], l_r[4];
        #pragma unroll
        for (int r = 0; r < 4; ++r) { m_r[r] = -1e30f; l_r[r] = 0.0f; }

        auto stage = [&](int kb, int base) {
            #pragma unroll
            for (int e = 0; e < 2; ++e) {
                const int D = (w * 2 + e) * 1024 + l * 16;
                const int row = D >> 7;
                const int src = D ^ ((row & 7) << 4);
                const int col = (src & 127) >> 1;
                GLOAD_LDS16(k16 + ((size_t)head * TT + (size_t)kb * 64 + row) * HD + col,
                            lds + base + (w * 2 + e) * 1024);
                GLOAD_LDS16(vt16 + ((size_t)head * HD + row) * TT + (size_t)kb * 64 + col,
                            lds + base + 8192 + (w * 2 + e) * 1024);
            }
        };

        int cur = 0;
        stage(kb0, 0);

        for (int kb = kb0; kb <= kb1; ++kb) {
            if (kb + 1 <= kb1) {
                stage(kb + 1, (cur ^ 1) * 16384);
                asm volatile("s_waitcnt vmcnt(4)" ::: "memory");
            } else {
                asm volatile("s_waitcnt vmcnt(0)" ::: "memory");
            }
            __builtin_amdgcn_s_barrier();
            __builtin_amdgcn_sched_barrier(0);

            const char* Ks  = lds + cur * 16384;
            const char* Vts = Ks + 8192;

            f32x4 s[4] = {};
            #pragma unroll
            for (int ks = 0; ks < 2; ++ks)
                #pragma unroll
                for (int kg = 0; kg < 4; ++kg) {
                    const int key = kg * 16 + (l & 15);
                    int b = key * 128 + ks * 64 + (l >> 4) * 16;
                    b ^= (key & 7) << 4;
                    short8 kf = *(const short8*)(Ks + b);
                    s[kg] = __builtin_amdgcn_mfma_f32_16x16x32_bf16(qa[ks], kf, s[kg], 0, 0, 0);
                }

            if (kb == qb) {   // diagonal tile only
                const int qg = qb * 64 + w * 16 + (l >> 4) * 4;
                #pragma unroll
                for (int kg = 0; kg < 4; ++kg)
                    #pragma unroll
                    for (int r = 0; r < 4; ++r)
                        if (kb * 64 + kg * 16 + (l & 15) > qg + r) s[kg][r] = -1e30f;
            }

            // in-lane defer-max check: no cross-lane traffic in steady state
            float ilmax[4];
            bool need = false;
            #pragma unroll
            for (int r = 0; r < 4; ++r) {
                const float m0 = fmaxf(fmaxf(s[0][r], s[1][r]), fmaxf(s[2][r], s[3][r]));
                ilmax[r] = m0;
                need = need || (m0 > m_r[r] + 8.0f);
            }
            if (__any(need)) {
                #pragma unroll
                for (int r = 0; r < 4; ++r) {
                    float m0 = ilmax[r];
                    m0 = fmaxf(m0, __shfl_xor(m0, 1));
                    m0 = fmaxf(m0, __shfl_xor(m0, 2));
                    m0 = fmaxf(m0, __shfl_xor(m0, 4));
                    m0 = fmaxf(m0, __shfl_xor(m0, 8));
                    const float mnew = fmaxf(m_r[r], m0);
                    const float al = EXP2F(m_r[r] - mnew);
                    m_r[r] = mnew;
                    l_r[r] *= al;
                    #pragma unroll
                    for (int dg = 0; dg < 4; ++dg)
                        yacc[dg][r] *= al;
                }
            }
            // P = exp2(s - m), partial row sums (cross-lane reduce deferred)
            #pragma unroll
            for (int r = 0; r < 4; ++r) {
                float ls = 0.0f;
                #pragma unroll
                for (int kg = 0; kg < 4; ++kg) {
                    float p = EXP2F(s[kg][r] - m_r[r]);
                    s[kg][r] = p;
                    ls += p;
                }
                l_r[r] += ls;
            }

            #pragma unroll
            for (int kg = 0; kg < 4; ++kg)
                #pragma unroll
                for (int r = 0; r < 4; ++r) {
                    const int qq = (l >> 4) * 4 + r;
                    int b = qq * 128 + (kg * 16 + (l & 15)) * 2;
                    b ^= (qq & 7) << 4;
                    *(ushortT*)(Pbase + b) = f2bf(s[kg][r]);
                }

            #pragma unroll
            for (int ks2 = 0; ks2 < 2; ++ks2) {
                const int qq = l & 15;
                int pb = qq * 128 + ks2 * 64 + (l >> 4) * 16;
                pb ^= (qq & 7) << 4;
                short8 pa = *(const short8*)(Pbase + pb);
                #pragma unroll
                for (int dg = 0; dg < 4; ++dg) {
                    const int dd = dg * 16 + (l & 15);
                    int vb = dd * 128 + ks2 * 64 + (l >> 4) * 16;
                    vb ^= (dd & 7) << 4;
                    short8 vf = *(const short8*)(Vts + vb);
                    yacc[dg] = __builtin_amdgcn_mfma_f32_16x16x32_bf16(pa, vf, yacc[dg], 0, 0, 0);
                }
            }
            __builtin_amdgcn_s_barrier();
            cur ^= 1;
        }

        // reduce deferred row-sums across the 16-lane group
        float lsum[4];
        #pragma unroll
        for (int r = 0; r < 4; ++r) {
            float t = l_r[r];
            t += __shfl_xor(t, 1);
            t += __shfl_xor(t, 2);
            t += __shfl_xor(t, 4);
            t += __shfl_xor(t, 8);
            lsum[r] = t;
        }

        if (ci < 0) {
            #pragma unroll
            for (int r = 0; r < 4; ++r) lsum[r] = 1.0f / lsum[r];
            #pragma unroll
            for (int dg = 0; dg < 4; ++dg)
                #pragma unroll
                for (int r = 0; r < 4; ++r) {
                    const int t = qb * 64 + w * 16 + (l >> 4) * 4 + r;
                    const int c = head * HD + dg * 16 + (l & 15);
                    y16[(size_t)t * CC + c] = f2bf(yacc[dg][r] * lsum[r]);
                }
        } else {
            char* pb = parts + (size_t)((head * 24 + (qb - QB_SPLIT)) * 2 + ci) * PSLOT_BYTES;
            float* yp = (float*)pb;
            float* mp = (float*)(pb + 16384);
            float* lp = mp + 64;
            #pragma unroll
            for (int dg = 0; dg < 4; ++dg)
                #pragma unroll
                for (int r = 0; r < 4; ++r) {
                    const int row = w * 16 + (l >> 4) * 4 + r;
                    const int col = dg * 16 + (l & 15);
                    yp[row * 64 + col] = yacc[dg][r];
                }
            if ((l & 15) == 0) {
                #pragma unroll
                for (int r = 0; r < 4; ++r) {
                    const int row = w * 16 + (l >> 4) * 4 + r;
                    mp[row] = m_r[r];
                    lp[row] = lsum[r];
                }
            }
        }
    }
}

// ---------------------------------------------------------------------------
// Merge the two partial chunks for qb in [QB_SPLIT, 64).
// ---------------------------------------------------------------------------
__global__ __launch_bounds__(256) void attn_combine(
    const char* __restrict__ parts, ushortT* __restrict__ y16)
{
    const int qb = QB_SPLIT + blockIdx.x;
    const int head = blockIdx.y;
    const int tid = threadIdx.x;
    const int row = tid >> 2;
    const int pc = tid & 3;

    const char* p0 = parts + (size_t)((head * 24 + (qb - QB_SPLIT)) * 2) * PSLOT_BYTES;
    const char* p1 = p0 + PSLOT_BYTES;
    const float* y0 = (const float*)p0;
    const float* y1 = (const float*)p1;
    const float* m0p = (const float*)(p0 + 16384);
    const float* m1p = (const float*)(p1 + 16384);
    const float m0 = m0p[row], m1 = m1p[row];
    const float l0 = m0p[64 + row], l1 = m1p[64 + row];
    const float M = fmaxf(m0, m1);
    const float w0 = EXP2F(m0 - M), w1 = EXP2F(m1 - M);
    const float Linv = 1.0f / (l0 * w0 + l1 * w1);

    const int t = qb * 64 + row;
    #pragma unroll
    for (int j = 0; j < 16; ++j) {
        const int c = pc * 16 + j;
        const float v = (y0[row * 64 + c] * w0 + y1[row * 64 + c] * w1) * Linv;
        y16[(size_t)t * CC + head * HD + c] = f2bf(v);
    }
}

extern "C" void kernel_launch(void* const* d_in, const int* in_sizes, int n_in,
                              void* d_out, int out_size, void* d_ws, size_t ws_size,
                              hipStream_t stream) {
    const float* x    = (const float*)d_in[0];
    const float* fcos = (const float*)d_in[1];
    const float* fsin = (const float*)d_in[2];
    const float* Wq   = (const float*)d_in[3];
    const float* Wk   = (const float*)d_in[4];
    const float* Wv   = (const float*)d_in[5];
    const float* Wo   = (const float*)d_in[6];
    float* out = (float*)d_out;

    char* ws = (char*)d_ws;
    ushortT* xb  = (ushortT*)(ws);                 // [0,8MB)  dead after QKV GEMMs
    ushortT* wqb = (ushortT*)(ws + (8u << 20));    // dead after Q GEMM
    ushortT* wkb = (ushortT*)(ws + (10u << 20));
    ushortT* wvb = (ushortT*)(ws + (12u << 20));
    ushortT* wob = (ushortT*)(ws + (14u << 20));   // LIVE until final GEMM
    ushortT* q16 = (ushortT*)(ws + (16u << 20));
    ushortT* k16 = (ushortT*)(ws + (24u << 20));
    ushortT* vt16 = (ushortT*)(ws + (32u << 20));
    ushortT* y16 = (ushortT*)(ws + (40u << 20));
    char* parts = ws;                              // [0, 12.38MB) dead region
    int* counter = (int*)(ws + (13u << 20));       // [13,14MB) free gap

    cvt_all<<<(TT * CC + 4 * CC * CC) / 4 / 256, 256, 0, stream>>>(
        x, Wq, Wk, Wv, Wo, xb, wqb, wkb, wvb, wob);

    dim3 ggrid(TT / 128, CC / 128);
    gemm_mfma<3><<<ggrid, 256, 0, stream>>>(xb, wqb, fcos, fsin, q16);
    gemm_mfma<1><<<ggrid, 256, 0, stream>>>(xb, wkb, fcos, fsin, k16);
    gemm_mfma<2><<<ggrid, 256, 0, stream>>>(xb, wvb, fcos, fsin, vt16);

    hipMemsetAsync(counter, 0, 4, stream);
    attn_mfma<<<1024, 256, 0, stream>>>(q16, k16, vt16, y16, parts, counter);

    dim3 cgrid(64 - QB_SPLIT, NH);
    attn_combine<<<cgrid, 256, 0, stream>>>(parts, y16);

    gemm_mfma<0><<<ggrid, 256, 0, stream>>>(y16, wob, fcos, fsin, out);
}

// Round 9
// 162.671 us; speedup vs baseline: 14.0086x; 1.1154x over previous
//
#include <hip/hip_runtime.h>
#include <hip/hip_bf16.h>
#include <math.h>

#define TT 4096
#define CC 1024
#define NH 16
#define HD 64

typedef unsigned short ushortT;
typedef __attribute__((ext_vector_type(8))) short short8;
typedef __attribute__((ext_vector_type(4))) float f32x4;

#define GLOAD_LDS16(gp, lp)                                                   \
    __builtin_amdgcn_global_load_lds(                                         \
        (const __attribute__((address_space(1))) void*)(gp),                  \
        (__attribute__((address_space(3))) void*)(lp), 16, 0, 0)

#define EXP2F(x) __builtin_amdgcn_exp2f(x)   // single v_exp_f32

__device__ __forceinline__ ushortT f2bf(float f) {
    __hip_bfloat16 h = __float2bfloat16(f);
    ushortT u; __builtin_memcpy(&u, &h, 2); return u;
}

// Partial-attention slot (f32): y[64][64] + m[64] + l[64] = 16384+256+256
#define PSLOT_BYTES 16896
#define QB_SPLIT 40   // qb >= QB_SPLIT uses 2 chunks; 16*24*2*16896 = 12.38MB < 13MB
#define NCHUNK 88

// ---------------------------------------------------------------------------
// One fused f32->bf16 conversion over x and the four weights.
// ---------------------------------------------------------------------------
__global__ __launch_bounds__(256) void cvt_all(
    const float* __restrict__ x,  const float* __restrict__ wq,
    const float* __restrict__ wk, const float* __restrict__ wv,
    const float* __restrict__ wo,
    ushortT* __restrict__ xb,  ushortT* __restrict__ wqb,
    ushortT* __restrict__ wkb, ushortT* __restrict__ wvb,
    ushortT* __restrict__ wob)
{
    const int i = (blockIdx.x * 256 + threadIdx.x) * 4;
    const int NX = TT * CC, NW = CC * CC;
    const float* s; ushortT* d; int off;
    if (i < NX)               { s = x;  d = xb;  off = i; }
    else if (i < NX + NW)     { s = wq; d = wqb; off = i - NX; }
    else if (i < NX + 2 * NW) { s = wk; d = wkb; off = i - NX - NW; }
    else if (i < NX + 3 * NW) { s = wv; d = wvb; off = i - NX - 2 * NW; }
    else                      { s = wo; d = wob; off = i - NX - 3 * NW; }
    float4 v = *(const float4*)(s + off);
    *(ushort4*)(d + off) = make_ushort4(f2bf(v.x), f2bf(v.y), f2bf(v.z), f2bf(v.w));
}

// ---------------------------------------------------------------------------
// Fused QKV GEMM: blockIdx.z selects weight + epilogue.
// z=0: Q = RoPE(x Wq^T) * 0.125*log2e -> bf16 [h][T][d]
// z=1: K = RoPE(x Wk^T)              -> bf16 [h][T][d]
// z=2: V^T with slot-permuted key dim -> bf16 [h][d][T']  (slot s=(k&15)*4+k>>4)
// 128x128 tile, BK=32, 3-buffer depth-2 counted-vmcnt pipeline.
// ---------------------------------------------------------------------------
__global__ __launch_bounds__(256) void gemm_qkv(
    const ushortT* __restrict__ A,
    const ushortT* __restrict__ Bq, const ushortT* __restrict__ Bk,
    const ushortT* __restrict__ Bv,
    const float* __restrict__ fcos, const float* __restrict__ fsin,
    ushortT* __restrict__ q16, ushortT* __restrict__ k16,
    ushortT* __restrict__ vt16)
{
    __shared__ char lds[49152];            // 3 x (A 8KB + B 8KB)

    const int z = blockIdx.z;
    const ushortT* B = (z == 0) ? Bq : (z == 1) ? Bk : Bv;

    const int lin = (int)(blockIdx.y * gridDim.x + blockIdx.x);
    const int nwg8 = (int)((gridDim.x * gridDim.y) >> 3);
    const int swz = (lin & 7) * nwg8 + (lin >> 3);
    const int bm = (swz % (int)gridDim.x) * 128;
    const int bn = (swz / (int)gridDim.x) * 128;
    const int tid = threadIdx.x;
    const int w = tid >> 6, l = tid & 63;
    const int wm = w >> 1, wn = w & 1;

    f32x4 acc[4][4] = {};

    auto stageg = [&](int kk, int base) {
        #pragma unroll
        for (int e = 0; e < 2; ++e) {
            const int D = (w * 2 + e) * 1024 + l * 16;
            const int r = D >> 6;
            const int c = (D & 63) >> 1;
            GLOAD_LDS16(A + (size_t)(bm + r) * CC + kk + c, lds + base + (w * 2 + e) * 1024);
            GLOAD_LDS16(B + (size_t)(bn + r) * CC + kk + c, lds + base + 8192 + (w * 2 + e) * 1024);
        }
    };

    stageg(0, 0);
    stageg(32, 16384);

    for (int kt = 0; kt < 32; ++kt) {
        const int cur = kt % 3;
        if (kt + 2 < 32) {
            stageg((kt + 2) * 32, ((kt + 2) % 3) * 16384);
            asm volatile("s_waitcnt vmcnt(8)" ::: "memory");
        } else if (kt + 1 < 32) {
            asm volatile("s_waitcnt vmcnt(4)" ::: "memory");
        } else {
            asm volatile("s_waitcnt vmcnt(0)" ::: "memory");
        }
        __builtin_amdgcn_s_barrier();
        __builtin_amdgcn_sched_barrier(0);

        const ushortT* As = (const ushortT*)(lds + cur * 16384);
        const ushortT* Bs = (const ushortT*)(lds + cur * 16384 + 8192);

        short8 af[4], bfr[4];
        #pragma unroll
        for (int i = 0; i < 4; ++i) {
            int row = wm * 64 + i * 16 + (l & 15);
            af[i] = *(const short8*)(As + row * 32 + (l >> 4) * 8);
        }
        #pragma unroll
        for (int j = 0; j < 4; ++j) {
            int row = wn * 64 + j * 16 + (l & 15);
            bfr[j] = *(const short8*)(Bs + row * 32 + (l >> 4) * 8);
        }
        #pragma unroll
        for (int i = 0; i < 4; ++i)
            #pragma unroll
            for (int j = 0; j < 4; ++j)
                acc[i][j] = __builtin_amdgcn_mfma_f32_16x16x32_bf16(af[i], bfr[j], acc[i][j], 0, 0, 0);
        __builtin_amdgcn_s_barrier();
    }

    if (z < 2) {
        const float rsc = (z == 0) ? 0.18033688011112042f : 1.0f;  // 0.125*log2(e)
        ushortT* dq = (z == 0) ? q16 : k16;
        float* cs = (float*)lds;
        float* sn = (float*)(lds + 16384);
        for (int idx = tid; idx < 128 * 32; idx += 256) {
            int rr = idx >> 5, cc2 = idx & 31;
            cs[idx] = fcos[(size_t)(bm + rr) * 32 + cc2];
            sn[idx] = fsin[(size_t)(bm + rr) * 32 + cc2];
        }
        __syncthreads();
        #pragma unroll
        for (int i = 0; i < 4; ++i)
            #pragma unroll
            for (int j = 0; j < 4; ++j)
                #pragma unroll
                for (int r = 0; r < 4; ++r) {
                    const int lt = wm * 64 + i * 16 + (l >> 4) * 4 + r;
                    const int o = bn + wn * 64 + j * 16 + (l & 15);
                    const float v = acc[i][j][r];
                    const float p = __shfl_xor(v, 1);
                    const int pp = (o & 63) >> 1;
                    const float cv = cs[lt * 32 + pp], sv = sn[lt * 32 + pp];
                    const float outv = ((o & 1) ? (p * sv + v * cv) : (v * cv - p * sv)) * rsc;
                    const int t = bm + lt, head = o >> 6, dd = o & 63;
                    dq[((size_t)head * TT + t) * HD + dd] = f2bf(outv);
                }
    } else {
        #pragma unroll
        for (int i = 0; i < 4; ++i)
            #pragma unroll
            for (int j = 0; j < 4; ++j)
                #pragma unroll
                for (int r = 0; r < 4; ++r) {
                    const int t = bm + wm * 64 + i * 16 + (l >> 4) * 4 + r;
                    const int o = bn + wn * 64 + j * 16 + (l & 15);
                    const int head = o >> 6, dd = o & 63;
                    const int k = t & 63;
                    const int slot = ((k & 15) << 2) | (k >> 4);
                    vt16[((size_t)(head * HD + dd)) * TT + (t & ~63) + slot] = f2bf(acc[i][j][r]);
                }
    }
}

// ---------------------------------------------------------------------------
// Final projection GEMM: out = y Wo^T, fp32 out [T][C].
// ---------------------------------------------------------------------------
__global__ __launch_bounds__(256) void gemm_out(
    const ushortT* __restrict__ A, const ushortT* __restrict__ B,
    float* __restrict__ dout)
{
    __shared__ char lds[49152];

    const int lin = (int)(blockIdx.y * gridDim.x + blockIdx.x);
    const int nwg8 = (int)((gridDim.x * gridDim.y) >> 3);
    const int swz = (lin & 7) * nwg8 + (lin >> 3);
    const int bm = (swz % (int)gridDim.x) * 128;
    const int bn = (swz / (int)gridDim.x) * 128;
    const int tid = threadIdx.x;
    const int w = tid >> 6, l = tid & 63;
    const int wm = w >> 1, wn = w & 1;

    f32x4 acc[4][4] = {};

    auto stageg = [&](int kk, int base) {
        #pragma unroll
        for (int e = 0; e < 2; ++e) {
            const int D = (w * 2 + e) * 1024 + l * 16;
            const int r = D >> 6;
            const int c = (D & 63) >> 1;
            GLOAD_LDS16(A + (size_t)(bm + r) * CC + kk + c, lds + base + (w * 2 + e) * 1024);
            GLOAD_LDS16(B + (size_t)(bn + r) * CC + kk + c, lds + base + 8192 + (w * 2 + e) * 1024);
        }
    };

    stageg(0, 0);
    stageg(32, 16384);

    for (int kt = 0; kt < 32; ++kt) {
        const int cur = kt % 3;
        if (kt + 2 < 32) {
            stageg((kt + 2) * 32, ((kt + 2) % 3) * 16384);
            asm volatile("s_waitcnt vmcnt(8)" ::: "memory");
        } else if (kt + 1 < 32) {
            asm volatile("s_waitcnt vmcnt(4)" ::: "memory");
        } else {
            asm volatile("s_waitcnt vmcnt(0)" ::: "memory");
        }
        __builtin_amdgcn_s_barrier();
        __builtin_amdgcn_sched_barrier(0);

        const ushortT* As = (const ushortT*)(lds + cur * 16384);
        const ushortT* Bs = (const ushortT*)(lds + cur * 16384 + 8192);

        short8 af[4], bfr[4];
        #pragma unroll
        for (int i = 0; i < 4; ++i) {
            int row = wm * 64 + i * 16 + (l & 15);
            af[i] = *(const short8*)(As + row * 32 + (l >> 4) * 8);
        }
        #pragma unroll
        for (int j = 0; j < 4; ++j) {
            int row = wn * 64 + j * 16 + (l & 15);
            bfr[j] = *(const short8*)(Bs + row * 32 + (l >> 4) * 8);
        }
        #pragma unroll
        for (int i = 0; i < 4; ++i)
            #pragma unroll
            for (int j = 0; j < 4; ++j)
                acc[i][j] = __builtin_amdgcn_mfma_f32_16x16x32_bf16(af[i], bfr[j], acc[i][j], 0, 0, 0);
        __builtin_amdgcn_s_barrier();
    }

    #pragma unroll
    for (int i = 0; i < 4; ++i)
        #pragma unroll
        for (int j = 0; j < 4; ++j)
            #pragma unroll
            for (int r = 0; r < 4; ++r) {
                const int t = bm + wm * 64 + i * 16 + (l >> 4) * 4 + r;
                const int o = bn + wn * 64 + j * 16 + (l & 15);
                dout[(size_t)t * CC + o] = acc[i][j][r];
            }
}

// ---------------------------------------------------------------------------
// bf16 MFMA flash attention, causal, split-KV, counted-vmcnt 2-phase pipeline,
// persistent blocks + work-stealing.  HEAD-MAJOR tickets for K/V L2 locality.
// Vt is slot-permuted (matching the packed P layout): PV contract unchanged.
// ---------------------------------------------------------------------------
__global__ __launch_bounds__(256) void attn_mfma(
    const ushortT* __restrict__ q16, const ushortT* __restrict__ k16,
    const ushortT* __restrict__ vt16, ushortT* __restrict__ y16,
    char* __restrict__ parts, int* __restrict__ counter)
{
    const int tid = threadIdx.x;
    const int w = tid >> 6, l = tid & 63;

    __shared__ char lds[40960];            // 2 x (K 8KB + Vt 8KB) + P 4x2KB
    char* Pbase = lds + 32768 + w * 2048;

    for (;;) {
        // ---- pull a ticket (broadcast through dead K-buffer word) ----
        if (tid == 0) {
            int tk0 = atomicAdd(counter, 1);
            *(int*)lds = tk0;
        }
        __syncthreads();
        const int tk = *(const int*)lds;
        __syncthreads();                   // all read before staging overwrites
        if (tk >= NCHUNK * NH) break;

        const int head = tk / NCHUNK;      // head-major: ~2 heads in flight
        const int cid = 87 - (tk - head * NCHUNK);
        int qb, ci, kb0, kb1;
        if (cid < QB_SPLIT) { qb = cid; ci = -1; kb0 = 0; kb1 = qb; }
        else {
            const int idx = cid - QB_SPLIT;
            qb = QB_SPLIT + (idx >> 1);
            ci = idx & 1;
            const int mid = (qb + 1) >> 1;
            kb0 = ci ? mid : 0;
            kb1 = ci ? qb : mid - 1;
        }

        const int qrow = qb * 64 + w * 16 + (l & 15);
        short8 qa[2];
        {
            const ushortT* qp = q16 + ((size_t)head * TT + qrow) * HD + (l >> 4) * 8;
            qa[0] = *(const short8*)(qp);
            qa[1] = *(const short8*)(qp + 32);
        }

        f32x4 yacc[4] = {};
        float m_r[4], l_r[4];
        #pragma unroll
        for (int r = 0; r < 4; ++r) { m_r[r] = -1e30f; l_r[r] = 0.0f; }

        auto stage = [&](int kb, int base) {
            #pragma unroll
            for (int e = 0; e < 2; ++e) {
                const int D = (w * 2 + e) * 1024 + l * 16;
                const int row = D >> 7;
                const int src = D ^ ((row & 7) << 4);
                const int col = (src & 127) >> 1;
                GLOAD_LDS16(k16 + ((size_t)head * TT + (size_t)kb * 64 + row) * HD + col,
                            lds + base + (w * 2 + e) * 1024);
                GLOAD_LDS16(vt16 + ((size_t)head * HD + row) * TT + (size_t)kb * 64 + col,
                            lds + base + 8192 + (w * 2 + e) * 1024);
            }
        };

        int cur = 0;
        stage(kb0, 0);

        for (int kb = kb0; kb <= kb1; ++kb) {
            if (kb + 1 <= kb1) {
                stage(kb + 1, (cur ^ 1) * 16384);
                asm volatile("s_waitcnt vmcnt(4)" ::: "memory");
            } else {
                asm volatile("s_waitcnt vmcnt(0)" ::: "memory");
            }
            __builtin_amdgcn_s_barrier();
            __builtin_amdgcn_sched_barrier(0);

            const char* Ks  = lds + cur * 16384;
            const char* Vts = Ks + 8192;

            f32x4 s[4] = {};
            #pragma unroll
            for (int ks = 0; ks < 2; ++ks)
                #pragma unroll
                for (int kg = 0; kg < 4; ++kg) {
                    const int key = kg * 16 + (l & 15);
                    int b = key * 128 + ks * 64 + (l >> 4) * 16;
                    b ^= (key & 7) << 4;
                    short8 kf = *(const short8*)(Ks + b);
                    s[kg] = __builtin_amdgcn_mfma_f32_16x16x32_bf16(qa[ks], kf, s[kg], 0, 0, 0);
                }

            if (kb == qb) {   // diagonal tile only
                const int qg = qb * 64 + w * 16 + (l >> 4) * 4;
                #pragma unroll
                for (int kg = 0; kg < 4; ++kg)
                    #pragma unroll
                    for (int r = 0; r < 4; ++r)
                        if (kb * 64 + kg * 16 + (l & 15) > qg + r) s[kg][r] = -1e30f;
            }

            // in-lane defer-max check: no cross-lane traffic in steady state
            float ilmax[4];
            bool need = false;
            #pragma unroll
            for (int r = 0; r < 4; ++r) {
                const float m0 = fmaxf(fmaxf(s[0][r], s[1][r]), fmaxf(s[2][r], s[3][r]));
                ilmax[r] = m0;
                need = need || (m0 > m_r[r] + 8.0f);
            }
            if (__any(need)) {
                #pragma unroll
                for (int r = 0; r < 4; ++r) {
                    float m0 = ilmax[r];
                    m0 = fmaxf(m0, __shfl_xor(m0, 1));
                    m0 = fmaxf(m0, __shfl_xor(m0, 2));
                    m0 = fmaxf(m0, __shfl_xor(m0, 4));
                    m0 = fmaxf(m0, __shfl_xor(m0, 8));
                    const float mnew = fmaxf(m_r[r], m0);
                    const float al = EXP2F(m_r[r] - mnew);
                    m_r[r] = mnew;
                    l_r[r] *= al;
                    #pragma unroll
                    for (int dg = 0; dg < 4; ++dg)
                        yacc[dg][r] *= al;
                }
            }
            // P = exp2(s - m), partial row sums (cross-lane reduce deferred)
            #pragma unroll
            for (int r = 0; r < 4; ++r) {
                float ls = 0.0f;
                #pragma unroll
                for (int kg = 0; kg < 4; ++kg) {
                    float p = EXP2F(s[kg][r] - m_r[r]);
                    s[kg][r] = p;
                    ls += p;
                }
                l_r[r] += ls;
            }

            // packed P-write: key kg*16+li -> slot li*4+kg (adjacent) -> one
            // 8B store per q-row via 2x v_cvt_pk_bf16_f32
            #pragma unroll
            for (int r = 0; r < 4; ++r) {
                const int qq = (l >> 4) * 4 + r;
                unsigned lo, hi;
                asm("v_cvt_pk_bf16_f32 %0, %1, %2" : "=v"(lo) : "v"(s[0][r]), "v"(s[1][r]));
                asm("v_cvt_pk_bf16_f32 %0, %1, %2" : "=v"(hi) : "v"(s[2][r]), "v"(s[3][r]));
                int b = qq * 128 + (l & 15) * 8;
                b ^= (qq & 7) << 4;
                *(uint2*)(Pbase + b) = make_uint2(lo, hi);
            }

            // Y += P V  (both operands in slot order -> same contraction)
            #pragma unroll
            for (int ks2 = 0; ks2 < 2; ++ks2) {
                const int qq = l & 15;
                int pb = qq * 128 + ks2 * 64 + (l >> 4) * 16;
                pb ^= (qq & 7) << 4;
                short8 pa = *(const short8*)(Pbase + pb);
                #pragma unroll
                for (int dg = 0; dg < 4; ++dg) {
                    const int dd = dg * 16 + (l & 15);
                    int vb = dd * 128 + ks2 * 64 + (l >> 4) * 16;
                    vb ^= (dd & 7) << 4;
                    short8 vf = *(const short8*)(Vts + vb);
                    yacc[dg] = __builtin_amdgcn_mfma_f32_16x16x32_bf16(pa, vf, yacc[dg], 0, 0, 0);
                }
            }
            __builtin_amdgcn_s_barrier();
            cur ^= 1;
        }

        // reduce deferred row-sums across the 16-lane group
        float lsum[4];
        #pragma unroll
        for (int r = 0; r < 4; ++r) {
            float t = l_r[r];
            t += __shfl_xor(t, 1);
            t += __shfl_xor(t, 2);
            t += __shfl_xor(t, 4);
            t += __shfl_xor(t, 8);
            lsum[r] = t;
        }

        if (ci < 0) {
            #pragma unroll
            for (int r = 0; r < 4; ++r) lsum[r] = 1.0f / lsum[r];
            #pragma unroll
            for (int dg = 0; dg < 4; ++dg)
                #pragma unroll
                for (int r = 0; r < 4; ++r) {
                    const int t = qb * 64 + w * 16 + (l >> 4) * 4 + r;
                    const int c = head * HD + dg * 16 + (l & 15);
                    y16[(size_t)t * CC + c] = f2bf(yacc[dg][r] * lsum[r]);
                }
        } else {
            char* pb = parts + (size_t)((head * 24 + (qb - QB_SPLIT)) * 2 + ci) * PSLOT_BYTES;
            float* yp = (float*)pb;
            float* mp = (float*)(pb + 16384);
            float* lp = mp + 64;
            #pragma unroll
            for (int dg = 0; dg < 4; ++dg)
                #pragma unroll
                for (int r = 0; r < 4; ++r) {
                    const int row = w * 16 + (l >> 4) * 4 + r;
                    const int col = dg * 16 + (l & 15);
                    yp[row * 64 + col] = yacc[dg][r];
                }
            if ((l & 15) == 0) {
                #pragma unroll
                for (int r = 0; r < 4; ++r) {
                    const int row = w * 16 + (l >> 4) * 4 + r;
                    mp[row] = m_r[r];
                    lp[row] = lsum[r];
                }
            }
        }
    }
}

// ---------------------------------------------------------------------------
// Merge the two partial chunks for qb in [QB_SPLIT, 64).
// ---------------------------------------------------------------------------
__global__ __launch_bounds__(256) void attn_combine(
    const char* __restrict__ parts, ushortT* __restrict__ y16)
{
    const int qb = QB_SPLIT + blockIdx.x;
    const int head = blockIdx.y;
    const int tid = threadIdx.x;
    const int row = tid >> 2;
    const int pc = tid & 3;

    const char* p0 = parts + (size_t)((head * 24 + (qb - QB_SPLIT)) * 2) * PSLOT_BYTES;
    const char* p1 = p0 + PSLOT_BYTES;
    const float* y0 = (const float*)p0;
    const float* y1 = (const float*)p1;
    const float* m0p = (const float*)(p0 + 16384);
    const float* m1p = (const float*)(p1 + 16384);
    const float m0 = m0p[row], m1 = m1p[row];
    const float l0 = m0p[64 + row], l1 = m1p[64 + row];
    const float M = fmaxf(m0, m1);
    const float w0 = EXP2F(m0 - M), w1 = EXP2F(m1 - M);
    const float Linv = 1.0f / (l0 * w0 + l1 * w1);

    const int t = qb * 64 + row;
    #pragma unroll
    for (int j = 0; j < 16; ++j) {
        const int c = pc * 16 + j;
        const float v = (y0[row * 64 + c] * w0 + y1[row * 64 + c] * w1) * Linv;
        y16[(size_t)t * CC + head * HD + c] = f2bf(v);
    }
}

extern "C" void kernel_launch(void* const* d_in, const int* in_sizes, int n_in,
                              void* d_out, int out_size, void* d_ws, size_t ws_size,
                              hipStream_t stream) {
    const float* x    = (const float*)d_in[0];
    const float* fcos = (const float*)d_in[1];
    const float* fsin = (const float*)d_in[2];
    const float* Wq   = (const float*)d_in[3];
    const float* Wk   = (const float*)d_in[4];
    const float* Wv   = (const float*)d_in[5];
    const float* Wo   = (const float*)d_in[6];
    float* out = (float*)d_out;

    char* ws = (char*)d_ws;
    ushortT* xb  = (ushortT*)(ws);                 // [0,8MB)  dead after QKV GEMMs
    ushortT* wqb = (ushortT*)(ws + (8u << 20));    // dead after QKV GEMM
    ushortT* wkb = (ushortT*)(ws + (10u << 20));
    ushortT* wvb = (ushortT*)(ws + (12u << 20));
    ushortT* wob = (ushortT*)(ws + (14u << 20));   // LIVE until final GEMM
    ushortT* q16 = (ushortT*)(ws + (16u << 20));
    ushortT* k16 = (ushortT*)(ws + (24u << 20));
    ushortT* vt16 = (ushortT*)(ws + (32u << 20));
    ushortT* y16 = (ushortT*)(ws + (40u << 20));
    char* parts = ws;                              // [0, 12.38MB) dead region
    int* counter = (int*)(ws + (13u << 20));       // [13,14MB) free gap

    cvt_all<<<(TT * CC + 4 * CC * CC) / 4 / 256, 256, 0, stream>>>(
        x, Wq, Wk, Wv, Wo, xb, wqb, wkb, wvb, wob);

    dim3 qkvgrid(TT / 128, CC / 128, 3);
    gemm_qkv<<<qkvgrid, 256, 0, stream>>>(xb, wqb, wkb, wvb, fcos, fsin,
                                          q16, k16, vt16);

    hipMemsetAsync(counter, 0, 4, stream);
    attn_mfma<<<1024, 256, 0, stream>>>(q16, k16, vt16, y16, parts, counter);

    dim3 cgrid(64 - QB_SPLIT, NH);
    attn_combine<<<cgrid, 256, 0, stream>>>(parts, y16);

    dim3 ggrid(TT / 128, CC / 128);
    gemm_out<<<ggrid, 256, 0, stream>>>(y16, wob, out);
}